// Round 2
// baseline (1765.188 us; speedup 1.0000x reference)
//
#include <hip/hip_runtime.h>

// ---------------------------------------------------------------- constants
constexpr int NC  = 16;    // n_chunks
constexpr int LL  = 1024;  // chunk len
constexpr int DM  = 512;   // d_model
constexpr int DI  = 1024;  // d_inner
constexpr int DS  = 16;    // d_state
constexpr int DTR = 32;    // dt_rank
constexpr int NH  = 8;     // heads
constexpr int DH  = 64;    // head dim
constexpr int NTOK = NC * LL;  // 16384

__device__ __forceinline__ float softplusf(float x) {
    return x > 20.f ? x : log1pf(__expf(x));
}
__device__ __forceinline__ float siluf(float x) {
    return x / (1.f + __expf(-x));
}

// ---------------------------------------------------------------- SGEMM
// C[M,N] = act(A[M,K]*B[K,N] + bias) (+ Cin).  Row-major, all dims divide tiles.
// BM*BK == 1024 and BN*BK == 1024 (one float4 per thread per tile for A and B).
template<int BM, int BN, int BK, int TM, int TN, int ACT, bool BIAS, bool ADDC>
__global__ __launch_bounds__(256)
void sgemm(const float* __restrict__ A, int lda,
           const float* __restrict__ B, int ldb,
           const float* __restrict__ bias,
           const float* __restrict__ Cin, int ldcin,
           float* __restrict__ C, int ldc,
           int K)
{
    __shared__ float As[BK][BM];
    __shared__ float Bs[BK][BN];
    const int tid = threadIdx.x;
    const int bm = blockIdx.y * BM;
    const int bn = blockIdx.x * BN;

    const int AR = tid / (BK / 4);
    const int AC = (tid % (BK / 4)) * 4;
    const int BR = tid / (BN / 4);
    const int BC = (tid % (BN / 4)) * 4;
    const int tx = tid % (BN / TN);
    const int ty = tid / (BN / TN);

    float acc[TM][TN] = {};

    for (int k0 = 0; k0 < K; k0 += BK) {
        float4 av = *(const float4*)&A[(bm + AR) * lda + k0 + AC];
        float4 bv = *(const float4*)&B[(k0 + BR) * ldb + bn + BC];
        __syncthreads();
        As[AC + 0][AR] = av.x;
        As[AC + 1][AR] = av.y;
        As[AC + 2][AR] = av.z;
        As[AC + 3][AR] = av.w;
        *(float4*)&Bs[BR][BC] = bv;
        __syncthreads();
#pragma unroll
        for (int kk = 0; kk < BK; ++kk) {
            float a[TM], b[TN];
#pragma unroll
            for (int i = 0; i < TM; i += 4)
                *(float4*)&a[i] = *(const float4*)&As[kk][ty * TM + i];
#pragma unroll
            for (int j = 0; j < TN; j += 4)
                *(float4*)&b[j] = *(const float4*)&Bs[kk][tx * TN + j];
#pragma unroll
            for (int i = 0; i < TM; ++i)
#pragma unroll
                for (int j = 0; j < TN; ++j)
                    acc[i][j] = fmaf(a[i], b[j], acc[i][j]);
        }
    }

#pragma unroll
    for (int i = 0; i < TM; ++i) {
        int row = bm + ty * TM + i;
#pragma unroll
        for (int j = 0; j < TN; ++j) {
            int col = bn + tx * TN + j;
            float v = acc[i][j];
            if (BIAS) v += bias[col];
            if (ACT == 1) v = softplusf(v);
            if (ADDC) v += Cin[row * ldcin + col];
            C[row * ldc + col] = v;
        }
    }
}

// ---------------------------------------------------------------- conv + silu
__global__ __launch_bounds__(256)
void conv_kernel(const float* __restrict__ xi, const float* __restrict__ conv_w,
                 const float* __restrict__ conv_b, float* __restrict__ xc)
{
    int idx = blockIdx.x * 256 + threadIdx.x;      // [NTOK*DI)
    int d = idx & (DI - 1);
    int ct = idx >> 10;
    int t = ct & (LL - 1);
    float4 w = *(const float4*)&conv_w[d * 4];
    float acc = conv_b[d];
    if (t >= 3) acc = fmaf(xi[(ct - 3) * DI + d], w.x, acc);
    if (t >= 2) acc = fmaf(xi[(ct - 2) * DI + d], w.y, acc);
    if (t >= 1) acc = fmaf(xi[(ct - 1) * DI + d], w.z, acc);
    acc = fmaf(xi[ct * DI + d], w.w, acc);
    xc[idx] = siluf(acc);
}

// ---------------------------------------------------------------- selective scan
// one LANE per (chunk, d, s): 16-lane group owns one channel, lane s carries
// state s. y_t = sum_s h*C via shfl_xor butterfly. 2-deep software pipeline.
// Reads dt from dty, writes y into dty in-place (store after last read of elem).
__global__ __launch_bounds__(256)
void scan_kernel(float* dty,
                 const float* __restrict__ xcp,
                 const float* __restrict__ zp,
                 const float* __restrict__ dbc,
                 const float* __restrict__ A_log,
                 const float* __restrict__ Dp)
{
    const int tid = threadIdx.x;
    const int c = blockIdx.x >> 6;                       // 64 blocks per chunk
    const int d = ((blockIdx.x & 63) << 4) + (tid >> 4); // 16 channels / block
    const int s = tid & 15;

    const float Areg = -__expf(A_log[d * DS + s]);
    const float Dpd = Dp[d];
    float h = 0.f;

    int idx  = c * LL * DI + d;          // +DI per t
    int bidx = c * LL * 64 + 32 + s;     // +64 per t  (B at +0, C at +16)

    float dt0 = dty[idx],      xc0 = xcp[idx],      z0 = zp[idx];
    float B0  = dbc[bidx],     C0  = dbc[bidx + 16];
    float dt1 = dty[idx + DI], xc1 = xcp[idx + DI], z1 = zp[idx + DI];
    float B1  = dbc[bidx + 64], C1 = dbc[bidx + 80];

    for (int t = 0; t < LL; t += 2) {
        {   // ---- step t (slot 0), prefetch t+2
            float cdt = dt0, cxc = xc0, cz = z0, cB = B0, cC = C0;
            if (t + 2 < LL) {
                int i2 = idx + 2 * DI, b2 = bidx + 2 * 64;
                dt0 = dty[i2]; xc0 = xcp[i2]; z0 = zp[i2];
                B0 = dbc[b2]; C0 = dbc[b2 + 16];
            }
            float dA = __expf(cdt * Areg);
            h = fmaf(dA, h, cdt * cxc * cB);
            float yt = h * cC;
            yt += __shfl_xor(yt, 1);
            yt += __shfl_xor(yt, 2);
            yt += __shfl_xor(yt, 4);
            yt += __shfl_xor(yt, 8);
            if (s == 0) dty[idx] = (yt + cxc * Dpd) * siluf(cz);
        }
        idx += DI; bidx += 64;
        {   // ---- step t+1 (slot 1), prefetch t+3
            float cdt = dt1, cxc = xc1, cz = z1, cB = B1, cC = C1;
            if (t + 3 < LL) {
                int i2 = idx + 2 * DI, b2 = bidx + 2 * 64;
                dt1 = dty[i2]; xc1 = xcp[i2]; z1 = zp[i2];
                B1 = dbc[b2]; C1 = dbc[b2 + 16];
            }
            float dA = __expf(cdt * Areg);
            h = fmaf(dA, h, cdt * cxc * cB);
            float yt = h * cC;
            yt += __shfl_xor(yt, 1);
            yt += __shfl_xor(yt, 2);
            yt += __shfl_xor(yt, 4);
            yt += __shfl_xor(yt, 8);
            if (s == 0) dty[idx] = (yt + cxc * Dpd) * siluf(cz);
        }
        idx += DI; bidx += 64;
    }
}

// ---------------------------------------------------------------- mean over L
__global__ __launch_bounds__(64)
void mean_kernel(const float* __restrict__ chunks, float* __restrict__ meanb)
{
    int j = blockIdx.x * 64 + threadIdx.x;
    int c = blockIdx.y;
    float s = 0.f;
    for (int t = 0; t < LL; ++t) s += chunks[(c * LL + t) * DM + j];
    meanb[c * DM + j] = s * (1.f / LL);
}

// ---------------------------------------------------------------- summaries
__global__ __launch_bounds__(256)
void summ_kernel(const float* __restrict__ meanb, const float* __restrict__ sum_w,
                 const float* __restrict__ sum_b, float* __restrict__ summ)
{
    int n = blockIdx.x * 256 + threadIdx.x;
    int c = blockIdx.y;
    float acc = sum_b[n];
    for (int k = 0; k < DM; ++k) acc = fmaf(meanb[c * DM + k], sum_w[k * DM + n], acc);
    summ[c * DM + n] = acc;
}

__global__ __launch_bounds__(256)
void kv_kernel(const float* __restrict__ summ, const float* __restrict__ wk,
               const float* __restrict__ wv, float* __restrict__ kb,
               float* __restrict__ vb)
{
    int n = blockIdx.x * 256 + threadIdx.x;
    int c = blockIdx.y;
    float ak = 0.f, av = 0.f;
    for (int k = 0; k < DM; ++k) {
        float s = summ[c * DM + k];
        ak = fmaf(s, wk[k * DM + n], ak);
        av = fmaf(s, wv[k * DM + n], av);
    }
    kb[c * DM + n] = ak;
    vb[c * DM + n] = av;
}

// ---------------------------------------------------------------- cross-attn
// block per token; scores+softmax in-block; attnv overwrites q row in-place.
__global__ __launch_bounds__(128)
void attn_kernel(float* qv,                      // [NTOK, DM] q in / attnv out
                 const float* __restrict__ kb,   // [NC, DM]
                 const float* __restrict__ vb)   // [NC, DM]
{
    __shared__ float sq[DM];
    __shared__ float sAttn[NH][NC];
    const int ct = blockIdx.x;
    const int c = ct >> 10;
    const int tid = threadIdx.x;

    *(float4*)&sq[tid * 4] = *(const float4*)&qv[ct * DM + tid * 4];
    __syncthreads();

    const int h = tid >> 4, j = tid & 15;
    const float* kr = kb + j * DM + h * DH;
    const float* qr = sq + h * DH;
    float s = 0.f;
#pragma unroll
    for (int d0 = 0; d0 < DH; d0 += 4) {
        float4 k4 = *(const float4*)&kr[d0];
        float4 q4 = *(const float4*)&qr[d0];
        s += q4.x * k4.x + q4.y * k4.y + q4.z * k4.z + q4.w * k4.w;
    }
    s *= 0.125f;                                  // 1/sqrt(64)
    if (j == c) s = -__builtin_inff();

    float m = s;
#pragma unroll
    for (int o = 1; o < 16; o <<= 1) m = fmaxf(m, __shfl_xor(m, o));
    float e = __expf(s - m);
    float sum = e;
#pragma unroll
    for (int o = 1; o < 16; o <<= 1) sum += __shfl_xor(sum, o);
    sAttn[h][j] = e / sum;
    __syncthreads();

#pragma unroll
    for (int r = 0; r < 4; ++r) {
        int o = r * 128 + tid;
        int h2 = o >> 6;
        float acc = 0.f;
#pragma unroll
        for (int jj = 0; jj < NC; ++jj)
            acc = fmaf(sAttn[h2][jj], vb[jj * DM + o], acc);
        qv[ct * DM + o] = acc;
    }
}

// ---------------------------------------------------------------- launch
extern "C" void kernel_launch(void* const* d_in, const int* in_sizes, int n_in,
                              void* d_out, int out_size, void* d_ws, size_t ws_size,
                              hipStream_t stream)
{
    const float* chunks   = (const float*)d_in[0];   // [16,1024,512]
    const float* in_proj  = (const float*)d_in[1];   // [512,2048]
    const float* conv_w   = (const float*)d_in[2];   // [1024,4]
    const float* conv_b   = (const float*)d_in[3];   // [1024]
    const float* x_proj   = (const float*)d_in[4];   // [1024,64]
    const float* dt_w     = (const float*)d_in[5];   // [32,1024]
    const float* dt_b     = (const float*)d_in[6];   // [1024]
    const float* A_log    = (const float*)d_in[7];   // [1024,16]
    const float* Dp       = (const float*)d_in[8];   // [1024]
    const float* out_proj = (const float*)d_in[9];   // [1024,512]
    const float* sum_w    = (const float*)d_in[10];  // [512,512]
    const float* sum_b    = (const float*)d_in[11];  // [512]
    const float* wq       = (const float*)d_in[12];  // [512,512]
    const float* wk       = (const float*)d_in[13];  // [512,512]
    const float* wv       = (const float*)d_in[14];  // [512,512]
    const float* wo       = (const float*)d_in[15];  // [512,512]
    float* out = (float*)d_out;

    // workspace layout (floats) — ~206 MB total
    float* ws   = (float*)d_ws;
    float* bufA = ws;                    // [NTOK,DI]  xi -> dt -> y
    float* bufB = bufA + NTOK * DI;      // [NTOK,DI]  z  -> q(512) -> attnv
    float* bufC = bufB + NTOK * DI;      // [NTOK,DI]  xc -> tok(512)
    float* dbc  = bufC + NTOK * DI;      // [NTOK,64]
    float* meanb= dbc + NTOK * 64;       // [16,512]
    float* summ = meanb + NC * DM;       // [16,512]
    float* kb   = summ + NC * DM;        // [16,512]
    float* vb   = kb + NC * DM;          // [16,512]

    dim3 blk256(256), blk128(128), blk64(64);

    // G1a: xi = chunks @ in_proj[:, :1024]
    sgemm<128, 128, 8, 8, 8, 0, false, false><<<dim3(DI / 128, NTOK / 128), blk256, 0, stream>>>(
        chunks, DM, in_proj, 2 * DI, nullptr, nullptr, 0, bufA, DI, DM);
    // G1b: z = chunks @ in_proj[:, 1024:]
    sgemm<128, 128, 8, 8, 8, 0, false, false><<<dim3(DI / 128, NTOK / 128), blk256, 0, stream>>>(
        chunks, DM, in_proj + DI, 2 * DI, nullptr, nullptr, 0, bufB, DI, DM);
    // conv + silu: xc
    conv_kernel<<<NTOK * DI / 256, blk256, 0, stream>>>(bufA, conv_w, conv_b, bufC);
    // G2: dbc = xc @ x_proj   (N=64)
    sgemm<64, 64, 16, 4, 4, 0, false, false><<<dim3(1, NTOK / 64), blk256, 0, stream>>>(
        bufC, DI, x_proj, 64, nullptr, nullptr, 0, dbc, 64, DI);
    // G3: dt = softplus(dbc[:, :32] @ dt_w + dt_b)  -> bufA (xi dead)
    sgemm<128, 128, 8, 8, 8, 1, true, false><<<dim3(DI / 128, NTOK / 128), blk256, 0, stream>>>(
        dbc, 64, dt_w, DI, dt_b, nullptr, 0, bufA, DI, DTR);
    // scan: y -> bufA in-place  (1024 blocks x 256 thr = 1 lane per (c,d,s))
    scan_kernel<<<NC * (DI / 16), blk256, 0, stream>>>(bufA, bufC, bufB, dbc, A_log, Dp);
    // G4: tok = y @ out_proj -> bufC (xc dead)
    sgemm<128, 128, 8, 8, 8, 0, false, false><<<dim3(DM / 128, NTOK / 128), blk256, 0, stream>>>(
        bufA, DI, out_proj, DM, nullptr, nullptr, 0, bufC, DM, DI);
    // summaries
    mean_kernel<<<dim3(DM / 64, NC), blk64, 0, stream>>>(chunks, meanb);
    summ_kernel<<<dim3(2, NC), blk256, 0, stream>>>(meanb, sum_w, sum_b, summ);
    kv_kernel<<<dim3(2, NC), blk256, 0, stream>>>(summ, wk, wv, kb, vb);
    // G5: q = tok @ wq -> bufB (z dead)
    sgemm<128, 128, 8, 8, 8, 0, false, false><<<dim3(DM / 128, NTOK / 128), blk256, 0, stream>>>(
        bufC, DM, wq, DM, nullptr, nullptr, 0, bufB, DM, DM);
    // attn: scores+softmax+attnv (in-place on bufB rows)
    attn_kernel<<<NTOK, blk128, 0, stream>>>(bufB, kb, vb);
    // G6: out = tok + attnv @ wo
    sgemm<128, 128, 8, 8, 8, 0, false, true><<<dim3(DM / 128, NTOK / 128), blk256, 0, stream>>>(
        bufB, DM, wo, DM, nullptr, bufC, DM, out, DM, DM);
}

// Round 4
// 1424.759 us; speedup vs baseline: 1.2389x; 1.2389x over previous
//
#include <hip/hip_runtime.h>

// ---------------------------------------------------------------- constants
constexpr int NC  = 16;    // n_chunks
constexpr int LL  = 1024;  // chunk len
constexpr int DM  = 512;   // d_model
constexpr int DI  = 1024;  // d_inner
constexpr int DS  = 16;    // d_state
constexpr int DTR = 32;    // dt_rank
constexpr int NH  = 8;     // heads
constexpr int DH  = 64;    // head dim
constexpr int NTOK = NC * LL;  // 16384
constexpr int NSEG = 16;   // scan segments
constexpr int TSEG = LL / NSEG;  // 64

__device__ __forceinline__ float softplusf(float x) {
    return x > 20.f ? x : log1pf(__expf(x));
}
__device__ __forceinline__ float siluf(float x) {
    return x / (1.f + __expf(-x));
}
__device__ __forceinline__ float fexp2(float x) {
    return __builtin_amdgcn_exp2f(x);             // v_exp_f32
}
__device__ __forceinline__ float q4(const float4& v, int r) {
    return r == 0 ? v.x : r == 1 ? v.y : r == 2 ? v.z : v.w;  // r compile-time
}

// ---------------------------------------------------------------- SGEMM
template<int BM, int BN, int BK, int TM, int TN, int ACT, bool BIAS, bool ADDC>
__global__ __launch_bounds__(256)
void sgemm(const float* __restrict__ A, int lda,
           const float* __restrict__ B, int ldb,
           const float* __restrict__ bias,
           const float* __restrict__ Cin, int ldcin,
           float* __restrict__ C, int ldc,
           int K)
{
    __shared__ float As[BK][BM];
    __shared__ float Bs[BK][BN];
    const int tid = threadIdx.x;
    const int bm = blockIdx.y * BM;
    const int bn = blockIdx.x * BN;

    const int AR = tid / (BK / 4);
    const int AC = (tid % (BK / 4)) * 4;
    const int BR = tid / (BN / 4);
    const int BC = (tid % (BN / 4)) * 4;
    const int tx = tid % (BN / TN);
    const int ty = tid / (BN / TN);

    float acc[TM][TN] = {};

    for (int k0 = 0; k0 < K; k0 += BK) {
        float4 av = *(const float4*)&A[(bm + AR) * lda + k0 + AC];
        float4 bv = *(const float4*)&B[(k0 + BR) * ldb + bn + BC];
        __syncthreads();
        As[AC + 0][AR] = av.x;
        As[AC + 1][AR] = av.y;
        As[AC + 2][AR] = av.z;
        As[AC + 3][AR] = av.w;
        *(float4*)&Bs[BR][BC] = bv;
        __syncthreads();
#pragma unroll
        for (int kk = 0; kk < BK; ++kk) {
            float a[TM], b[TN];
#pragma unroll
            for (int i = 0; i < TM; i += 4)
                *(float4*)&a[i] = *(const float4*)&As[kk][ty * TM + i];
#pragma unroll
            for (int j = 0; j < TN; j += 4)
                *(float4*)&b[j] = *(const float4*)&Bs[kk][tx * TN + j];
#pragma unroll
            for (int i = 0; i < TM; ++i)
#pragma unroll
                for (int j = 0; j < TN; ++j)
                    acc[i][j] = fmaf(a[i], b[j], acc[i][j]);
        }
    }

#pragma unroll
    for (int i = 0; i < TM; ++i) {
        int row = bm + ty * TM + i;
#pragma unroll
        for (int j = 0; j < TN; ++j) {
            int col = bn + tx * TN + j;
            float v = acc[i][j];
            if (BIAS) v += bias[col];
            if (ACT == 1) v = softplusf(v);
            if (ADDC) v += Cin[row * ldcin + col];
            C[row * ldc + col] = v;
        }
    }
}

// ---------------------------------------------------------------- conv + silu
__global__ __launch_bounds__(256)
void conv_kernel(const float* __restrict__ xi, const float* __restrict__ conv_w,
                 const float* __restrict__ conv_b, float* __restrict__ xc)
{
    int idx = blockIdx.x * 256 + threadIdx.x;      // [NTOK*DI)
    int d = idx & (DI - 1);
    int ct = idx >> 10;
    int t = ct & (LL - 1);
    float4 w = *(const float4*)&conv_w[d * 4];
    float acc = conv_b[d];
    if (t >= 3) acc = fmaf(xi[(ct - 3) * DI + d], w.x, acc);
    if (t >= 2) acc = fmaf(xi[(ct - 2) * DI + d], w.y, acc);
    if (t >= 1) acc = fmaf(xi[(ct - 1) * DI + d], w.z, acc);
    acc = fmaf(xi[ct * DI + d], w.w, acc);
    xc[idx] = siluf(acc);
}

// ---------------------------------------------------------------- scan S1
// lane = (c, d, seg); local scan from h=0 over TSEG steps; store h_end + sum(dt).
// hseg layout: [c][seg][d][16]; Dsum: [c][seg][d].
__global__ __launch_bounds__(256)
void scan1_kernel(const float* __restrict__ dtp, const float* __restrict__ xcp,
                  const float* __restrict__ dbc, const float* __restrict__ A_log,
                  float* __restrict__ hseg, float* __restrict__ Dsum)
{
    const int tid = threadIdx.x;
    int b = blockIdx.x;
    const int dblk = b & 3;
    const int seg  = (b >> 2) & (NSEG - 1);
    const int c    = b >> 6;
    const int d = dblk * 256 + tid;

    float A2[DS];
#pragma unroll
    for (int s = 0; s < DS; ++s)
        A2[s] = -__expf(A_log[d * DS + s]) * 1.44269504f;
    float h[DS] = {};
    float Dacc = 0.f;

    int idx  = (c * LL + seg * TSEG) * DI + d;
    int bidx = (c * LL + seg * TSEG) * 64 + 32;

    for (int t = 0; t < TSEG; ++t) {
        float dt = dtp[idx];
        float xc = xcp[idx];
        float4 Bq0 = *(const float4*)&dbc[bidx];
        float4 Bq1 = *(const float4*)&dbc[bidx + 4];
        float4 Bq2 = *(const float4*)&dbc[bidx + 8];
        float4 Bq3 = *(const float4*)&dbc[bidx + 12];
        Dacc += dt;
        float dtx = dt * xc;
#pragma unroll
        for (int qi = 0; qi < 4; ++qi) {
            float4 Bv = qi == 0 ? Bq0 : qi == 1 ? Bq1 : qi == 2 ? Bq2 : Bq3;
#pragma unroll
            for (int r = 0; r < 4; ++r) {
                int s = qi * 4 + r;
                float dA = fexp2(dt * A2[s]);
                h[s] = fmaf(dA, h[s], dtx * q4(Bv, r));
            }
        }
        idx += DI; bidx += 64;
    }

    int ho = ((c * NSEG + seg) * DI + d) * DS;
#pragma unroll
    for (int s = 0; s < DS; s += 4)
        *(float4*)&hseg[ho + s] = make_float4(h[s], h[s + 1], h[s + 2], h[s + 3]);
    Dsum[(c * NSEG + seg) * DI + d] = Dacc;
}

// ---------------------------------------------------------------- scan S2
// lane = (c, d, s); sequential combine across segments, in-place on hseg:
// h_in[0]=0; h_in[k] = exp(A*Dsum[k-1])*h_in[k-1] + h_end[k-1].
__global__ __launch_bounds__(256)
void scan2_kernel(float* hseg, const float* __restrict__ Dsum,
                  const float* __restrict__ A_log)
{
    int g = blockIdx.x * 256 + threadIdx.x;      // (c*DI+d)*16 + s
    const int s  = g & 15;
    const int cd = g >> 4;
    const int d = cd & (DI - 1);
    const int c = cd >> 10;
    const float A2 = -__expf(A_log[d * DS + s]) * 1.44269504f;

    float h = 0.f;
#pragma unroll
    for (int k = 0; k < NSEG; ++k) {
        int o = ((c * NSEG + k) * DI + d) * DS + s;
        float he = hseg[o];
        float Dk = Dsum[(c * NSEG + k) * DI + d];
        hseg[o] = h;                              // h_in for segment k
        h = fmaf(fexp2(A2 * Dk), h, he);          // carry to k+1
    }
}

// ---------------------------------------------------------------- scan S3
// lane = (c, d, seg); full scan from h_in with y + gating epilogue.
// reads dt from dty, writes y in-place.
__global__ __launch_bounds__(256)
void scan3_kernel(float* dty, const float* __restrict__ xcp,
                  const float* __restrict__ zp, const float* __restrict__ dbc,
                  const float* __restrict__ A_log, const float* __restrict__ Dp,
                  const float* __restrict__ hseg)
{
    const int tid = threadIdx.x;
    int b = blockIdx.x;
    const int dblk = b & 3;
    const int seg  = (b >> 2) & (NSEG - 1);
    const int c    = b >> 6;
    const int d = dblk * 256 + tid;

    float A2[DS];
#pragma unroll
    for (int s = 0; s < DS; ++s)
        A2[s] = -__expf(A_log[d * DS + s]) * 1.44269504f;
    const float Dpd = Dp[d];

    float h[DS];
    int ho = ((c * NSEG + seg) * DI + d) * DS;
#pragma unroll
    for (int s = 0; s < DS; s += 4) {
        float4 hv = *(const float4*)&hseg[ho + s];
        h[s] = hv.x; h[s + 1] = hv.y; h[s + 2] = hv.z; h[s + 3] = hv.w;
    }

    int idx  = (c * LL + seg * TSEG) * DI + d;
    int bidx = (c * LL + seg * TSEG) * 64 + 32;

    float ndt = dty[idx], nxc = xcp[idx], nz = zp[idx];

    for (int t = 0; t < TSEG; ++t) {
        float dt = ndt, xc = nxc, z = nz;
        if (t + 1 < TSEG) {
            ndt = dty[idx + DI]; nxc = xcp[idx + DI]; nz = zp[idx + DI];
        }
        float4 Bq0 = *(const float4*)&dbc[bidx];
        float4 Bq1 = *(const float4*)&dbc[bidx + 4];
        float4 Bq2 = *(const float4*)&dbc[bidx + 8];
        float4 Bq3 = *(const float4*)&dbc[bidx + 12];
        float4 Cq0 = *(const float4*)&dbc[bidx + 16];
        float4 Cq1 = *(const float4*)&dbc[bidx + 20];
        float4 Cq2 = *(const float4*)&dbc[bidx + 24];
        float4 Cq3 = *(const float4*)&dbc[bidx + 28];
        float dtx = dt * xc;
        float yt = 0.f;
#pragma unroll
        for (int qi = 0; qi < 4; ++qi) {
            float4 Bv = qi == 0 ? Bq0 : qi == 1 ? Bq1 : qi == 2 ? Bq2 : Bq3;
            float4 Cv = qi == 0 ? Cq0 : qi == 1 ? Cq1 : qi == 2 ? Cq2 : Cq3;
#pragma unroll
            for (int r = 0; r < 4; ++r) {
                int s = qi * 4 + r;
                float dA = fexp2(dt * A2[s]);
                h[s] = fmaf(dA, h[s], dtx * q4(Bv, r));
                yt = fmaf(h[s], q4(Cv, r), yt);
            }
        }
        dty[idx] = (yt + xc * Dpd) * siluf(z);
        idx += DI; bidx += 64;
    }
}

// ---------------------------------------------------------------- mean over L
__global__ __launch_bounds__(64)
void mean_kernel(const float* __restrict__ chunks, float* __restrict__ meanb)
{
    int j = blockIdx.x * 64 + threadIdx.x;
    int c = blockIdx.y;
    float s = 0.f;
    for (int t = 0; t < LL; ++t) s += chunks[(c * LL + t) * DM + j];
    meanb[c * DM + j] = s * (1.f / LL);
}

// ---------------------------------------------------------------- summaries
__global__ __launch_bounds__(256)
void summ_kernel(const float* __restrict__ meanb, const float* __restrict__ sum_w,
                 const float* __restrict__ sum_b, float* __restrict__ summ)
{
    int n = blockIdx.x * 256 + threadIdx.x;
    int c = blockIdx.y;
    float acc = sum_b[n];
    for (int k = 0; k < DM; ++k) acc = fmaf(meanb[c * DM + k], sum_w[k * DM + n], acc);
    summ[c * DM + n] = acc;
}

__global__ __launch_bounds__(256)
void kv_kernel(const float* __restrict__ summ, const float* __restrict__ wk,
               const float* __restrict__ wv, float* __restrict__ kb,
               float* __restrict__ vb)
{
    int n = blockIdx.x * 256 + threadIdx.x;
    int c = blockIdx.y;
    float ak = 0.f, av = 0.f;
    for (int k = 0; k < DM; ++k) {
        float s = summ[c * DM + k];
        ak = fmaf(s, wk[k * DM + n], ak);
        av = fmaf(s, wv[k * DM + n], av);
    }
    kb[c * DM + n] = ak;
    vb[c * DM + n] = av;
}

// ---------------------------------------------------------------- cross-attn
__global__ __launch_bounds__(128)
void attn_kernel(float* qv,                      // [NTOK, DM] q in / attnv out
                 const float* __restrict__ kb,   // [NC, DM]
                 const float* __restrict__ vb)   // [NC, DM]
{
    __shared__ float sq[DM];
    __shared__ float sAttn[NH][NC];
    const int ct = blockIdx.x;
    const int c = ct >> 10;
    const int tid = threadIdx.x;

    *(float4*)&sq[tid * 4] = *(const float4*)&qv[ct * DM + tid * 4];
    __syncthreads();

    const int h = tid >> 4, j = tid & 15;
    const float* kr = kb + j * DM + h * DH;
    const float* qr = sq + h * DH;
    float s = 0.f;
#pragma unroll
    for (int d0 = 0; d0 < DH; d0 += 4) {
        float4 k4 = *(const float4*)&kr[d0];
        float4 qv4 = *(const float4*)&qr[d0];
        s += qv4.x * k4.x + qv4.y * k4.y + qv4.z * k4.z + qv4.w * k4.w;
    }
    s *= 0.125f;                                  // 1/sqrt(64)
    if (j == c) s = -__builtin_inff();

    float m = s;
#pragma unroll
    for (int o = 1; o < 16; o <<= 1) m = fmaxf(m, __shfl_xor(m, o));
    float e = __expf(s - m);
    float sum = e;
#pragma unroll
    for (int o = 1; o < 16; o <<= 1) sum += __shfl_xor(sum, o);
    sAttn[h][j] = e / sum;
    __syncthreads();

#pragma unroll
    for (int r = 0; r < 4; ++r) {
        int o = r * 128 + tid;
        int h2 = o >> 6;
        float acc = 0.f;
#pragma unroll
        for (int jj = 0; jj < NC; ++jj)
            acc = fmaf(sAttn[h2][jj], vb[jj * DM + o], acc);
        qv[ct * DM + o] = acc;
    }
}

// ---------------------------------------------------------------- launch
extern "C" void kernel_launch(void* const* d_in, const int* in_sizes, int n_in,
                              void* d_out, int out_size, void* d_ws, size_t ws_size,
                              hipStream_t stream)
{
    const float* chunks   = (const float*)d_in[0];
    const float* in_proj  = (const float*)d_in[1];
    const float* conv_w   = (const float*)d_in[2];
    const float* conv_b   = (const float*)d_in[3];
    const float* x_proj   = (const float*)d_in[4];
    const float* dt_w     = (const float*)d_in[5];
    const float* dt_b     = (const float*)d_in[6];
    const float* A_log    = (const float*)d_in[7];
    const float* Dp       = (const float*)d_in[8];
    const float* out_proj = (const float*)d_in[9];
    const float* sum_w    = (const float*)d_in[10];
    const float* sum_b    = (const float*)d_in[11];
    const float* wq       = (const float*)d_in[12];
    const float* wk       = (const float*)d_in[13];
    const float* wv       = (const float*)d_in[14];
    const float* wo       = (const float*)d_in[15];
    float* out = (float*)d_out;

    // workspace layout (floats) — ~218 MB total
    float* ws   = (float*)d_ws;
    float* bufA = ws;                    // [NTOK,DI]  xi -> dt -> y
    float* bufB = bufA + NTOK * DI;      // [NTOK,DI]  z  -> q(512) -> attnv
    float* bufC = bufB + NTOK * DI;      // [NTOK,DI]  xc -> tok(512)
    float* dbc  = bufC + NTOK * DI;      // [NTOK,64]
    float* meanb= dbc + NTOK * 64;       // [16,512]
    float* summ = meanb + NC * DM;       // [16,512]
    float* kb   = summ + NC * DM;        // [16,512]
    float* vb   = kb + NC * DM;          // [16,512]
    float* hseg = vb + NC * DM;          // [NC,NSEG,DI,DS]  h_end -> h_in
    float* Dsum = hseg + NC * NSEG * DI * DS;  // [NC,NSEG,DI]

    dim3 blk256(256), blk128(128), blk64(64);

    // G1a: xi = chunks @ in_proj[:, :1024]
    sgemm<128, 128, 8, 8, 8, 0, false, false><<<dim3(DI / 128, NTOK / 128), blk256, 0, stream>>>(
        chunks, DM, in_proj, 2 * DI, nullptr, nullptr, 0, bufA, DI, DM);
    // G1b: z = chunks @ in_proj[:, 1024:]
    sgemm<128, 128, 8, 8, 8, 0, false, false><<<dim3(DI / 128, NTOK / 128), blk256, 0, stream>>>(
        chunks, DM, in_proj + DI, 2 * DI, nullptr, nullptr, 0, bufB, DI, DM);
    // conv + silu: xc
    conv_kernel<<<NTOK * DI / 256, blk256, 0, stream>>>(bufA, conv_w, conv_b, bufC);
    // G2: dbc = xc @ x_proj
    sgemm<64, 64, 16, 4, 4, 0, false, false><<<dim3(1, NTOK / 64), blk256, 0, stream>>>(
        bufC, DI, x_proj, 64, nullptr, nullptr, 0, dbc, 64, DI);
    // G3: dt = softplus(dbc[:, :32] @ dt_w + dt_b)  -> bufA (xi dead)
    sgemm<128, 128, 8, 8, 8, 1, true, false><<<dim3(DI / 128, NTOK / 128), blk256, 0, stream>>>(
        dbc, 64, dt_w, DI, dt_b, nullptr, 0, bufA, DI, DTR);
    // scan: 3-phase segmented
    scan1_kernel<<<NC * NSEG * (DI / 256), blk256, 0, stream>>>(bufA, bufC, dbc, A_log, hseg, Dsum);
    scan2_kernel<<<NC * DI * DS / 256, blk256, 0, stream>>>(hseg, Dsum, A_log);
    scan3_kernel<<<NC * NSEG * (DI / 256), blk256, 0, stream>>>(bufA, bufC, bufB, dbc, A_log, Dp, hseg);
    // G4: tok = y @ out_proj -> bufC (xc dead)
    sgemm<128, 128, 8, 8, 8, 0, false, false><<<dim3(DM / 128, NTOK / 128), blk256, 0, stream>>>(
        bufA, DI, out_proj, DM, nullptr, nullptr, 0, bufC, DM, DI);
    // summaries
    mean_kernel<<<dim3(DM / 64, NC), blk64, 0, stream>>>(chunks, meanb);
    summ_kernel<<<dim3(2, NC), blk256, 0, stream>>>(meanb, sum_w, sum_b, summ);
    kv_kernel<<<dim3(2, NC), blk256, 0, stream>>>(summ, wk, wv, kb, vb);
    // G5: q = tok @ wq -> bufB (z dead)
    sgemm<128, 128, 8, 8, 8, 0, false, false><<<dim3(DM / 128, NTOK / 128), blk256, 0, stream>>>(
        bufC, DM, wq, DM, nullptr, nullptr, 0, bufB, DM, DM);
    // attn
    attn_kernel<<<NTOK, blk128, 0, stream>>>(bufB, kb, vb);
    // G6: out = tok + attnv @ wo
    sgemm<128, 128, 8, 8, 8, 0, false, true><<<dim3(DM / 128, NTOK / 128), blk256, 0, stream>>>(
        bufB, DM, wo, DM, nullptr, bufC, DM, out, DM, DM);
}

// Round 6
// 1390.007 us; speedup vs baseline: 1.2699x; 1.0250x over previous
//
#include <hip/hip_runtime.h>

// ---------------------------------------------------------------- constants
constexpr int NC  = 16;    // n_chunks
constexpr int LL  = 1024;  // chunk len
constexpr int DM  = 512;   // d_model
constexpr int DI  = 1024;  // d_inner
constexpr int DS  = 16;    // d_state
constexpr int NH  = 8;     // heads
constexpr int DH  = 64;    // head dim
constexpr int NTOK = NC * LL;  // 16384
constexpr int NSEG = 16;   // scan segments
constexpr int TSEG = LL / NSEG;  // 64

typedef unsigned short u16;
typedef __attribute__((ext_vector_type(8))) short bf16x8;
typedef __attribute__((ext_vector_type(4))) float f32x4;

__device__ __forceinline__ float softplusf(float x) {
    return x > 20.f ? x : log1pf(__expf(x));
}
__device__ __forceinline__ float siluf(float x) {
    return x / (1.f + __expf(-x));
}
__device__ __forceinline__ float fexp2(float x) {
    return __builtin_amdgcn_exp2f(x);             // v_exp_f32
}
__device__ __forceinline__ float q4(const float4& v, int r) {
    return r == 0 ? v.x : r == 1 ? v.y : r == 2 ? v.z : v.w;  // r compile-time
}
__device__ __forceinline__ u16 f2bf(float f) {    // RNE fp32 -> bf16 bits
    union { float f; unsigned u; } v; v.f = f;
    unsigned u = v.u;
    return (u16)((u + 0x7FFFu + ((u >> 16) & 1u)) >> 16);
}
__device__ __forceinline__ float bf2f(u16 h) {
    union { unsigned u; float f; } v; v.u = (unsigned)h << 16;
    return v.f;
}

// ---------------------------------------------------------------- split (linear)
__global__ __launch_bounds__(256)
void split_kernel(const float* __restrict__ in, u16* __restrict__ hi,
                  u16* __restrict__ lo, int n4)
{
    int i = blockIdx.x * 256 + threadIdx.x;
    if (i >= n4) return;
    float4 v = ((const float4*)in)[i];
    ushort4 h, l;
    h.x = f2bf(v.x); l.x = f2bf(v.x - bf2f(h.x));
    h.y = f2bf(v.y); l.y = f2bf(v.y - bf2f(h.y));
    h.z = f2bf(v.z); l.z = f2bf(v.z - bf2f(h.z));
    h.w = f2bf(v.w); l.w = f2bf(v.w - bf2f(h.w));
    ((ushort4*)hi)[i] = h;
    ((ushort4*)lo)[i] = l;
}

// ---------------------------------------------------------------- splitT
// weights fp32 [K][N] -> bf16 hi/lo [N][K] via LDS 64x64 tile transpose
__global__ __launch_bounds__(256)
void splitT_kernel(const float* __restrict__ in, u16* __restrict__ hi,
                   u16* __restrict__ lo, int K, int N)
{
    __shared__ float tile[64][65];
    const int k0 = blockIdx.y * 64, n0 = blockIdx.x * 64;
    const int tr = threadIdx.x >> 6, tc = threadIdx.x & 63;
#pragma unroll
    for (int i = 0; i < 16; ++i) {
        int r = tr * 16 + i;
        tile[r][tc] = in[(size_t)(k0 + r) * N + n0 + tc];
    }
    __syncthreads();
#pragma unroll
    for (int i = 0; i < 16; ++i) {
        int r = tr * 16 + i;
        float v = tile[tc][r];                    // in[k0+tc][n0+r]
        u16 h = f2bf(v);
        u16 l = f2bf(v - bf2f(h));
        size_t o = (size_t)(n0 + r) * K + k0 + tc;
        hi[o] = h;
        lo[o] = l;
    }
}

// ---------------------------------------------------------------- MFMA GEMM (bf16x3)
// C = Ah*Bh + Ah*Bl + Al*Bh (+Cin); A split [M][K], B split [N][K] (pre-transposed).
// 128x128 tile, BK=64, 512 thr (8 waves 2x4), 16x16x32 MFMA, XOR-swizzled LDS.
template<bool ADDC>
__global__ __launch_bounds__(512)
void mgemm(const u16* __restrict__ Ah, const u16* __restrict__ Al,
           const u16* __restrict__ Bh, const u16* __restrict__ Bl,
           const float* __restrict__ Cin, int ldcin,
           float* __restrict__ C, float* __restrict__ C2, int nsplit, int ldc,
           int K)
{
    __shared__ u16 lds[4][128][64];               // Ah, Al, Bh, Bl tiles (64 KB)
    const int tid = threadIdx.x;
    const int bm = blockIdx.y * 128, bn = blockIdx.x * 128;
    const int lane = tid & 63;
    const int w = tid >> 6, wr = w >> 2, wc = w & 3;

    const int srow = tid >> 3;                    // 0..63 (+64 via rstep)
    const int schunk = tid & 7;
    const u16* srcs[4] = { Ah + (size_t)(bm + srow) * K,
                           Al + (size_t)(bm + srow) * K,
                           Bh + (size_t)(bn + srow) * K,
                           Bl + (size_t)(bn + srow) * K };
    const size_t rstep = (size_t)64 * K;

    f32x4 acc[4][2];
#pragma unroll
    for (int i = 0; i < 4; ++i)
#pragma unroll
        for (int j = 0; j < 2; ++j)
            acc[i][j] = (f32x4){0.f, 0.f, 0.f, 0.f};

    uint4 pre[8];
    const int nkt = K >> 6;

#define STAGE_LOAD(kt)                                                          \
    {                                                                           \
        _Pragma("unroll")                                                       \
        for (int T = 0; T < 4; ++T)                                             \
            _Pragma("unroll")                                                   \
            for (int j = 0; j < 2; ++j)                                         \
                pre[T * 2 + j] = *(const uint4*)(srcs[T] + j * rstep +          \
                                                 (kt) * 64 + schunk * 8);       \
    }

    STAGE_LOAD(0);
    for (int kt = 0; kt < nkt; ++kt) {
        const int pc = schunk ^ (srow & 7);
#pragma unroll
        for (int T = 0; T < 4; ++T) {
            *(uint4*)&lds[T][srow][pc * 8] = pre[T * 2 + 0];
            *(uint4*)&lds[T][srow + 64][pc * 8] = pre[T * 2 + 1];
        }
        __syncthreads();
        if (kt + 1 < nkt) STAGE_LOAD(kt + 1);
#pragma unroll
        for (int ks = 0; ks < 2; ++ks) {
            bf16x8 ah[4], al[4], bh[2], bl[2];
            const int kc = ks * 4 + (lane >> 4);
#pragma unroll
            for (int mi = 0; mi < 4; ++mi) {
                int row = wr * 64 + mi * 16 + (lane & 15);
                int rc = kc ^ (row & 7);
                ah[mi] = *(const bf16x8*)&lds[0][row][rc * 8];
                al[mi] = *(const bf16x8*)&lds[1][row][rc * 8];
            }
#pragma unroll
            for (int ni = 0; ni < 2; ++ni) {
                int col = wc * 32 + ni * 16 + (lane & 15);
                int rc = kc ^ (col & 7);
                bh[ni] = *(const bf16x8*)&lds[2][col][rc * 8];
                bl[ni] = *(const bf16x8*)&lds[3][col][rc * 8];
            }
#pragma unroll
            for (int mi = 0; mi < 4; ++mi)
#pragma unroll
                for (int ni = 0; ni < 2; ++ni) {
                    acc[mi][ni] = __builtin_amdgcn_mfma_f32_16x16x32_bf16(
                        ah[mi], bh[ni], acc[mi][ni], 0, 0, 0);
                    acc[mi][ni] = __builtin_amdgcn_mfma_f32_16x16x32_bf16(
                        ah[mi], bl[ni], acc[mi][ni], 0, 0, 0);
                    acc[mi][ni] = __builtin_amdgcn_mfma_f32_16x16x32_bf16(
                        al[mi], bh[ni], acc[mi][ni], 0, 0, 0);
                }
        }
        __syncthreads();
    }
#undef STAGE_LOAD

    // epilogue: C/D layout col = lane&15, row = (lane>>4)*4 + r
#pragma unroll
    for (int mi = 0; mi < 4; ++mi) {
        int row0 = bm + wr * 64 + mi * 16 + (lane >> 4) * 4;
#pragma unroll
        for (int ni = 0; ni < 2; ++ni) {
            int col = bn + wc * 32 + ni * 16 + (lane & 15);
            float* Cp = C; int cc = col;
            if (col >= nsplit) { Cp = C2; cc = col - nsplit; }
#pragma unroll
            for (int r = 0; r < 4; ++r) {
                float v = acc[mi][ni][r];
                if (ADDC) v += Cin[(size_t)(row0 + r) * ldcin + col];
                Cp[(size_t)(row0 + r) * ldc + cc] = v;
            }
        }
    }
}

// ---------------------------------------------------------------- SGEMM (fp32, small)
template<int BM, int BN, int BK, int TM, int TN, int ACT, bool BIAS, bool ADDC>
__global__ __launch_bounds__(256)
void sgemm(const float* __restrict__ A, int lda,
           const float* __restrict__ B, int ldb,
           const float* __restrict__ bias,
           const float* __restrict__ Cin, int ldcin,
           float* __restrict__ C, int ldc,
           int K)
{
    __shared__ float As[BK][BM];
    __shared__ float Bs[BK][BN];
    const int tid = threadIdx.x;
    const int bm = blockIdx.y * BM;
    const int bn = blockIdx.x * BN;

    const int AR = tid / (BK / 4);
    const int AC = (tid % (BK / 4)) * 4;
    const int BR = tid / (BN / 4);
    const int BC = (tid % (BN / 4)) * 4;
    const int tx = tid % (BN / TN);
    const int ty = tid / (BN / TN);

    float acc[TM][TN] = {};

    for (int k0 = 0; k0 < K; k0 += BK) {
        float4 av = *(const float4*)&A[(bm + AR) * lda + k0 + AC];
        float4 bv = *(const float4*)&B[(k0 + BR) * ldb + bn + BC];
        __syncthreads();
        As[AC + 0][AR] = av.x;
        As[AC + 1][AR] = av.y;
        As[AC + 2][AR] = av.z;
        As[AC + 3][AR] = av.w;
        *(float4*)&Bs[BR][BC] = bv;
        __syncthreads();
#pragma unroll
        for (int kk = 0; kk < BK; ++kk) {
            float a[TM], b[TN];
#pragma unroll
            for (int i = 0; i < TM; i += 4)
                *(float4*)&a[i] = *(const float4*)&As[kk][ty * TM + i];
#pragma unroll
            for (int j = 0; j < TN; j += 4)
                *(float4*)&b[j] = *(const float4*)&Bs[kk][tx * TN + j];
#pragma unroll
            for (int i = 0; i < TM; ++i)
#pragma unroll
                for (int j = 0; j < TN; ++j)
                    acc[i][j] = fmaf(a[i], b[j], acc[i][j]);
        }
    }

#pragma unroll
    for (int i = 0; i < TM; ++i) {
        int row = bm + ty * TM + i;
#pragma unroll
        for (int j = 0; j < TN; ++j) {
            int col = bn + tx * TN + j;
            float v = acc[i][j];
            if (BIAS) v += bias[col];
            if (ACT == 1) v = softplusf(v);
            if (ADDC) v += Cin[row * ldcin + col];
            C[row * ldc + col] = v;
        }
    }
}

// ---------------------------------------------------------------- conv + silu
__global__ __launch_bounds__(256)
void conv_kernel(const float* __restrict__ xi, const float* __restrict__ conv_w,
                 const float* __restrict__ conv_b, float* __restrict__ xc)
{
    int idx = blockIdx.x * 256 + threadIdx.x;      // [NTOK*DI)
    int d = idx & (DI - 1);
    int ct = idx >> 10;
    int t = ct & (LL - 1);
    float4 w = *(const float4*)&conv_w[d * 4];
    float acc = conv_b[d];
    if (t >= 3) acc = fmaf(xi[(ct - 3) * DI + d], w.x, acc);
    if (t >= 2) acc = fmaf(xi[(ct - 2) * DI + d], w.y, acc);
    if (t >= 1) acc = fmaf(xi[(ct - 1) * DI + d], w.z, acc);
    acc = fmaf(xi[ct * DI + d], w.w, acc);
    xc[idx] = siluf(acc);
}

// ---------------------------------------------------------------- scan S1
__global__ __launch_bounds__(256)
void scan1_kernel(const float* __restrict__ dtp, const float* __restrict__ xcp,
                  const float* __restrict__ dbc, const float* __restrict__ A_log,
                  float* __restrict__ hseg, float* __restrict__ Dsum)
{
    const int tid = threadIdx.x;
    int b = blockIdx.x;
    const int dblk = b & 3;
    const int seg  = (b >> 2) & (NSEG - 1);
    const int c    = b >> 6;
    const int d = dblk * 256 + tid;

    float A2[DS];
#pragma unroll
    for (int s = 0; s < DS; ++s)
        A2[s] = -__expf(A_log[d * DS + s]) * 1.44269504f;
    float h[DS] = {};
    float Dacc = 0.f;

    int idx  = (c * LL + seg * TSEG) * DI + d;
    int bidx = (c * LL + seg * TSEG) * 64 + 32;

    for (int t = 0; t < TSEG; ++t) {
        float dt = dtp[idx];
        float xc = xcp[idx];
        float4 Bq0 = *(const float4*)&dbc[bidx];
        float4 Bq1 = *(const float4*)&dbc[bidx + 4];
        float4 Bq2 = *(const float4*)&dbc[bidx + 8];
        float4 Bq3 = *(const float4*)&dbc[bidx + 12];
        Dacc += dt;
        float dtx = dt * xc;
#pragma unroll
        for (int qi = 0; qi < 4; ++qi) {
            float4 Bv = qi == 0 ? Bq0 : qi == 1 ? Bq1 : qi == 2 ? Bq2 : Bq3;
#pragma unroll
            for (int r = 0; r < 4; ++r) {
                int s = qi * 4 + r;
                float dA = fexp2(dt * A2[s]);
                h[s] = fmaf(dA, h[s], dtx * q4(Bv, r));
            }
        }
        idx += DI; bidx += 64;
    }

    int ho = ((c * NSEG + seg) * DI + d) * DS;
#pragma unroll
    for (int s = 0; s < DS; s += 4)
        *(float4*)&hseg[ho + s] = make_float4(h[s], h[s + 1], h[s + 2], h[s + 3]);
    Dsum[(c * NSEG + seg) * DI + d] = Dacc;
}

// ---------------------------------------------------------------- scan S2
__global__ __launch_bounds__(256)
void scan2_kernel(float* hseg, const float* __restrict__ Dsum,
                  const float* __restrict__ A_log)
{
    int g = blockIdx.x * 256 + threadIdx.x;      // (c*DI+d)*16 + s
    const int s  = g & 15;
    const int cd = g >> 4;
    const int d = cd & (DI - 1);
    const int c = cd >> 10;
    const float A2 = -__expf(A_log[d * DS + s]) * 1.44269504f;

    float h = 0.f;
#pragma unroll
    for (int k = 0; k < NSEG; ++k) {
        int o = ((c * NSEG + k) * DI + d) * DS + s;
        float he = hseg[o];
        float Dk = Dsum[(c * NSEG + k) * DI + d];
        hseg[o] = h;                              // h_in for segment k
        h = fmaf(fexp2(A2 * Dk), h, he);          // carry to k+1
    }
}

// ---------------------------------------------------------------- scan S3
__global__ __launch_bounds__(256)
void scan3_kernel(float* dty, const float* __restrict__ xcp,
                  const float* __restrict__ zp, const float* __restrict__ dbc,
                  const float* __restrict__ A_log, const float* __restrict__ Dp,
                  const float* __restrict__ hseg)
{
    const int tid = threadIdx.x;
    int b = blockIdx.x;
    const int dblk = b & 3;
    const int seg  = (b >> 2) & (NSEG - 1);
    const int c    = b >> 6;
    const int d = dblk * 256 + tid;

    float A2[DS];
#pragma unroll
    for (int s = 0; s < DS; ++s)
        A2[s] = -__expf(A_log[d * DS + s]) * 1.44269504f;
    const float Dpd = Dp[d];

    float h[DS];
    int ho = ((c * NSEG + seg) * DI + d) * DS;
#pragma unroll
    for (int s = 0; s < DS; s += 4) {
        float4 hv = *(const float4*)&hseg[ho + s];
        h[s] = hv.x; h[s + 1] = hv.y; h[s + 2] = hv.z; h[s + 3] = hv.w;
    }

    int idx  = (c * LL + seg * TSEG) * DI + d;
    int bidx = (c * LL + seg * TSEG) * 64 + 32;

    float ndt = dty[idx], nxc = xcp[idx], nz = zp[idx];

    for (int t = 0; t < TSEG; ++t) {
        float dt = ndt, xc = nxc, z = nz;
        if (t + 1 < TSEG) {
            ndt = dty[idx + DI]; nxc = xcp[idx + DI]; nz = zp[idx + DI];
        }
        float4 Bq0 = *(const float4*)&dbc[bidx];
        float4 Bq1 = *(const float4*)&dbc[bidx + 4];
        float4 Bq2 = *(const float4*)&dbc[bidx + 8];
        float4 Bq3 = *(const float4*)&dbc[bidx + 12];
        float4 Cq0 = *(const float4*)&dbc[bidx + 16];
        float4 Cq1 = *(const float4*)&dbc[bidx + 20];
        float4 Cq2 = *(const float4*)&dbc[bidx + 24];
        float4 Cq3 = *(const float4*)&dbc[bidx + 28];
        float dtx = dt * xc;
        float yt = 0.f;
#pragma unroll
        for (int qi = 0; qi < 4; ++qi) {
            float4 Bv = qi == 0 ? Bq0 : qi == 1 ? Bq1 : qi == 2 ? Bq2 : Bq3;
            float4 Cv = qi == 0 ? Cq0 : qi == 1 ? Cq1 : qi == 2 ? Cq2 : Cq3;
#pragma unroll
            for (int r = 0; r < 4; ++r) {
                int s = qi * 4 + r;
                float dA = fexp2(dt * A2[s]);
                h[s] = fmaf(dA, h[s], dtx * q4(Bv, r));
                yt = fmaf(h[s], q4(Cv, r), yt);
            }
        }
        dty[idx] = (yt + xc * Dpd) * siluf(z);
        idx += DI; bidx += 64;
    }
}

// ---------------------------------------------------------------- mean over L
__global__ __launch_bounds__(64)
void mean_kernel(const float* __restrict__ chunks, float* __restrict__ meanb)
{
    int j = blockIdx.x * 64 + threadIdx.x;
    int c = blockIdx.y;
    float s = 0.f;
    for (int t = 0; t < LL; ++t) s += chunks[(c * LL + t) * DM + j];
    meanb[c * DM + j] = s * (1.f / LL);
}

// ---------------------------------------------------------------- summaries
__global__ __launch_bounds__(256)
void summ_kernel(const float* __restrict__ meanb, const float* __restrict__ sum_w,
                 const float* __restrict__ sum_b, float* __restrict__ summ)
{
    int n = blockIdx.x * 256 + threadIdx.x;
    int c = blockIdx.y;
    float acc = sum_b[n];
    for (int k = 0; k < DM; ++k) acc = fmaf(meanb[c * DM + k], sum_w[k * DM + n], acc);
    summ[c * DM + n] = acc;
}

__global__ __launch_bounds__(256)
void kv_kernel(const float* __restrict__ summ, const float* __restrict__ wk,
               const float* __restrict__ wv, float* __restrict__ kb,
               float* __restrict__ vb)
{
    int n = blockIdx.x * 256 + threadIdx.x;
    int c = blockIdx.y;
    float ak = 0.f, av = 0.f;
    for (int k = 0; k < DM; ++k) {
        float s = summ[c * DM + k];
        ak = fmaf(s, wk[k * DM + n], ak);
        av = fmaf(s, wv[k * DM + n], av);
    }
    kb[c * DM + n] = ak;
    vb[c * DM + n] = av;
}

// ---------------------------------------------------------------- cross-attn
__global__ __launch_bounds__(128)
void attn_kernel(float* qv,                      // [NTOK, DM] q in / attnv out
                 const float* __restrict__ kb,   // [NC, DM]
                 const float* __restrict__ vb)   // [NC, DM]
{
    __shared__ float sq[DM];
    __shared__ float sAttn[NH][NC];
    const int ct = blockIdx.x;
    const int c = ct >> 10;
    const int tid = threadIdx.x;

    *(float4*)&sq[tid * 4] = *(const float4*)&qv[ct * DM + tid * 4];
    __syncthreads();

    const int h = tid >> 4, j = tid & 15;
    const float* kr = kb + j * DM + h * DH;
    const float* qr = sq + h * DH;
    float s = 0.f;
#pragma unroll
    for (int d0 = 0; d0 < DH; d0 += 4) {
        float4 k4 = *(const float4*)&kr[d0];
        float4 qv4 = *(const float4*)&qr[d0];
        s += qv4.x * k4.x + qv4.y * k4.y + qv4.z * k4.z + qv4.w * k4.w;
    }
    s *= 0.125f;                                  // 1/sqrt(64)
    if (j == c) s = -__builtin_inff();

    float m = s;
#pragma unroll
    for (int o = 1; o < 16; o <<= 1) m = fmaxf(m, __shfl_xor(m, o));
    float e = __expf(s - m);
    float sum = e;
#pragma unroll
    for (int o = 1; o < 16; o <<= 1) sum += __shfl_xor(sum, o);
    sAttn[h][j] = e / sum;
    __syncthreads();

#pragma unroll
    for (int r = 0; r < 4; ++r) {
        int o = r * 128 + tid;
        int h2 = o >> 6;
        float acc = 0.f;
#pragma unroll
        for (int jj = 0; jj < NC; ++jj)
            acc = fmaf(sAttn[h2][jj], vb[jj * DM + o], acc);
        qv[ct * DM + o] = acc;
    }
}

// ---------------------------------------------------------------- launch
extern "C" void kernel_launch(void* const* d_in, const int* in_sizes, int n_in,
                              void* d_out, int out_size, void* d_ws, size_t ws_size,
                              hipStream_t stream)
{
    const float* chunks   = (const float*)d_in[0];
    const float* in_proj  = (const float*)d_in[1];
    const float* conv_w   = (const float*)d_in[2];
    const float* conv_b   = (const float*)d_in[3];
    const float* x_proj   = (const float*)d_in[4];
    const float* dt_w     = (const float*)d_in[5];
    const float* dt_b     = (const float*)d_in[6];
    const float* A_log    = (const float*)d_in[7];
    const float* Dp       = (const float*)d_in[8];
    const float* out_proj = (const float*)d_in[9];
    const float* sum_w    = (const float*)d_in[10];
    const float* sum_b    = (const float*)d_in[11];
    const float* wq       = (const float*)d_in[12];
    const float* wk       = (const float*)d_in[13];
    const float* wv       = (const float*)d_in[14];
    const float* wo       = (const float*)d_in[15];
    float* out = (float*)d_out;

    // -------- workspace layout: identical footprint to R4 (~213 MB)
    float* ws   = (float*)d_ws;
    float* bufA = ws;                            // [NTOK,DI] xi -> dt -> y -> {tokH/L, avH/L}
    float* bufB = bufA + (size_t)NTOK * DI;      // [NTOK,DI] z -> q -> attnv
    float* bufC = bufB + (size_t)NTOK * DI;      // [NTOK,DI] {chH/L} -> xc -> {yH/L}
    float* dbc  = bufC + (size_t)NTOK * DI;      // [NTOK,64]
    float* meanb= dbc + (size_t)NTOK * 64;       // [16,512]
    float* summ = meanb + NC * DM;
    float* kb   = summ + NC * DM;
    float* vb   = kb + NC * DM;
    float* hseg = vb + NC * DM;                  // [NC,NSEG,DI,DS]; aliases ipT then {opT,wqT,woT}
    float* Dsum = hseg + (size_t)NC * NSEG * DI * DS;  // [NC,NSEG,DI]

    // u16 aliases (all within existing fp32 buffers; lifetimes verified)
    u16* chH  = (u16*)bufC;                      // [NTOK,DM]  dead after G1
    u16* chL  = chH + (size_t)NTOK * DM;
    u16* yH   = (u16*)bufC;                      // [NTOK,DI]  written after scan3 (xc dead)
    u16* yL   = yH + (size_t)NTOK * DI;          //  = 64 MB exactly (all of bufC)
    u16* tokH = (u16*)bufA;                      // [NTOK,DM]  written after G4 (y dead)
    u16* tokL = tokH + (size_t)NTOK * DM;
    u16* avH  = (u16*)bufA + (size_t)NTOK * DI;  // bufA second half
    u16* avL  = avH + (size_t)NTOK * DM;
    u16* ipTh = (u16*)hseg;                      // [2048,512] dead after G1; hseg written later
    u16* ipTl = ipTh + (size_t)2048 * 512;
    u16* opTh = (u16*)hseg;                      // written after scan3 (hseg dead)
    u16* opTl = opTh + (size_t)512 * 1024;
    u16* wqTh = opTl + (size_t)512 * 1024;
    u16* wqTl = wqTh + (size_t)512 * 512;
    u16* woTh = wqTl + (size_t)512 * 512;
    u16* woTl = woTh + (size_t)512 * 512;

    dim3 blk512(512), blk256(256), blk128(128), blk64(64);
    const int BIG = 1 << 30;

    // ---- split in_proj (into hseg region) + chunks (into bufC)
    splitT_kernel<<<dim3(2048 / 64, 512 / 64), blk256, 0, stream>>>(in_proj, ipTh, ipTl, 512, 2048);
    split_kernel<<<NTOK * DM / 4 / 256, blk256, 0, stream>>>(chunks, chH, chL, NTOK * DM / 4);
    // G1: [xi | z] = chunks @ in_proj  (M=16384, N=2048, K=512)
    mgemm<false><<<dim3(2048 / 128, NTOK / 128), blk512, 0, stream>>>(
        chH, chL, ipTh, ipTl, nullptr, 0, bufA, bufB, 1024, DI, DM);
    // conv + silu: xc -> bufC (overwrites chH/chL, dead)
    conv_kernel<<<NTOK * DI / 256, blk256, 0, stream>>>(bufA, conv_w, conv_b, bufC);
    // G2: dbc = xc @ x_proj (fp32, N=64)
    sgemm<64, 64, 16, 4, 4, 0, false, false><<<dim3(1, NTOK / 64), blk256, 0, stream>>>(
        bufC, DI, x_proj, 64, nullptr, nullptr, 0, dbc, 64, DI);
    // G3: dt = softplus(dbc[:, :32] @ dt_w + dt_b) -> bufA (xi dead)
    sgemm<128, 128, 8, 8, 8, 1, true, false><<<dim3(DI / 128, NTOK / 128), blk256, 0, stream>>>(
        dbc, 64, dt_w, DI, dt_b, nullptr, 0, bufA, DI, 32);
    // scan: 3-phase segmented; scan1 overwrites ipT region with hseg (ipT dead)
    scan1_kernel<<<NC * NSEG * (DI / 256), blk256, 0, stream>>>(bufA, bufC, dbc, A_log, hseg, Dsum);
    scan2_kernel<<<NC * DI * DS / 256, blk256, 0, stream>>>(hseg, Dsum, A_log);
    scan3_kernel<<<NC * NSEG * (DI / 256), blk256, 0, stream>>>(bufA, bufC, bufB, dbc, A_log, Dp, hseg);
    // split y (bufA) -> yH/yL in bufC (xc dead)
    split_kernel<<<NTOK * DI / 4 / 256, blk256, 0, stream>>>(bufA, yH, yL, NTOK * DI / 4);
    // split remaining weights into hseg region (hseg dead after scan3)
    splitT_kernel<<<dim3(512 / 64, 1024 / 64), blk256, 0, stream>>>(out_proj, opTh, opTl, 1024, 512);
    splitT_kernel<<<dim3(512 / 64, 512 / 64), blk256, 0, stream>>>(wq, wqTh, wqTl, 512, 512);
    splitT_kernel<<<dim3(512 / 64, 512 / 64), blk256, 0, stream>>>(wo, woTh, woTl, 512, 512);
    // G4: tok = y @ out_proj -> d_out used as scratch (fully overwritten)
    mgemm<false><<<dim3(DM / 128, NTOK / 128), blk512, 0, stream>>>(
        yH, yL, opTh, opTl, nullptr, 0, out, nullptr, BIG, DM, DI);
    // summaries
    mean_kernel<<<dim3(DM / 64, NC), blk64, 0, stream>>>(chunks, meanb);
    summ_kernel<<<dim3(2, NC), blk256, 0, stream>>>(meanb, sum_w, sum_b, summ);
    kv_kernel<<<dim3(2, NC), blk256, 0, stream>>>(summ, wk, wv, kb, vb);
    // split tok (d_out) -> tokH/tokL in bufA (y dead)
    split_kernel<<<NTOK * DM / 4 / 256, blk256, 0, stream>>>(out, tokH, tokL, NTOK * DM / 4);
    // G5: q = tok @ wq -> bufB (z dead)
    mgemm<false><<<dim3(DM / 128, NTOK / 128), blk512, 0, stream>>>(
        tokH, tokL, wqTh, wqTl, nullptr, 0, bufB, nullptr, BIG, DM, DM);
    // attn: in-place on bufB rows
    attn_kernel<<<NTOK, blk128, 0, stream>>>(bufB, kb, vb);
    // split attnv (bufB) -> avH/avL in bufA second half (tokH/tokL dead after G5)
    split_kernel<<<NTOK * DM / 4 / 256, blk256, 0, stream>>>(bufB, avH, avL, NTOK * DM / 4);
    // G6: out = tok + attnv @ wo  (Cin = d_out read-then-write, same thread)
    mgemm<true><<<dim3(DM / 128, NTOK / 128), blk512, 0, stream>>>(
        avH, avL, woTh, woTl, out, DM, out, nullptr, BIG, DM, DM);
}

// Round 7
// 893.270 us; speedup vs baseline: 1.9761x; 1.5561x over previous
//
#include <hip/hip_runtime.h>

// ---------------------------------------------------------------- constants
constexpr int NC  = 16;    // n_chunks
constexpr int LL  = 1024;  // chunk len
constexpr int DM  = 512;   // d_model
constexpr int DI  = 1024;  // d_inner
constexpr int DS  = 16;    // d_state
constexpr int NH  = 8;     // heads
constexpr int DH  = 64;    // head dim
constexpr int NTOK = NC * LL;  // 16384
constexpr int NSEG = 16;   // scan segments
constexpr int TSEG = LL / NSEG;  // 64

typedef unsigned short u16;
typedef __attribute__((ext_vector_type(8))) short bf16x8;
typedef __attribute__((ext_vector_type(4))) float f32x4;

__device__ __forceinline__ float softplusf(float x) {
    return x > 20.f ? x : log1pf(__expf(x));
}
__device__ __forceinline__ float siluf(float x) {
    return x / (1.f + __expf(-x));
}
__device__ __forceinline__ float fexp2(float x) {
    return __builtin_amdgcn_exp2f(x);             // v_exp_f32
}
__device__ __forceinline__ float q4(const float4& v, int r) {
    return r == 0 ? v.x : r == 1 ? v.y : r == 2 ? v.z : v.w;  // r compile-time
}
__device__ __forceinline__ u16 f2bf(float f) {    // RNE fp32 -> bf16 bits
    union { float f; unsigned u; } v; v.f = f;
    unsigned u = v.u;
    return (u16)((u + 0x7FFFu + ((u >> 16) & 1u)) >> 16);
}
__device__ __forceinline__ float bf2f(u16 h) {
    union { unsigned u; float f; } v; v.u = (unsigned)h << 16;
    return v.f;
}

// ---------------------------------------------------------------- split (linear)
__global__ __launch_bounds__(256)
void split_kernel(const float* __restrict__ in, u16* __restrict__ hi,
                  u16* __restrict__ lo, int n4)
{
    int i = blockIdx.x * 256 + threadIdx.x;
    if (i >= n4) return;
    float4 v = ((const float4*)in)[i];
    ushort4 h, l;
    h.x = f2bf(v.x); l.x = f2bf(v.x - bf2f(h.x));
    h.y = f2bf(v.y); l.y = f2bf(v.y - bf2f(h.y));
    h.z = f2bf(v.z); l.z = f2bf(v.z - bf2f(h.z));
    h.w = f2bf(v.w); l.w = f2bf(v.w - bf2f(h.w));
    ((ushort4*)hi)[i] = h;
    ((ushort4*)lo)[i] = l;
}

// ---------------------------------------------------------------- splitT
// weights fp32 [K][N] -> bf16 hi/lo [N][K] via LDS 64x64 tile transpose
__global__ __launch_bounds__(256)
void splitT_kernel(const float* __restrict__ in, u16* __restrict__ hi,
                   u16* __restrict__ lo, int K, int N)
{
    __shared__ float tile[64][65];
    const int k0 = blockIdx.y * 64, n0 = blockIdx.x * 64;
    const int tr = threadIdx.x >> 6, tc = threadIdx.x & 63;
#pragma unroll
    for (int i = 0; i < 16; ++i) {
        int r = tr * 16 + i;
        tile[r][tc] = in[(size_t)(k0 + r) * N + n0 + tc];
    }
    __syncthreads();
#pragma unroll
    for (int i = 0; i < 16; ++i) {
        int r = tr * 16 + i;
        float v = tile[tc][r];                    // in[k0+tc][n0+r]
        u16 h = f2bf(v);
        u16 l = f2bf(v - bf2f(h));
        size_t o = (size_t)(n0 + r) * K + k0 + tc;
        hi[o] = h;
        lo[o] = l;
    }
}

// ---------------------------------------------------------------- MFMA GEMM (bf16x3)
// C = Ah*Bh + Ah*Bl + Al*Bh (+Cin); A split [M][K], B split [N][K].
// 128x128 tile, BK=64, 512 thr (8 waves 2x4), global_load_lds staging into
// 128KB double-buffered LDS (linear dest, pre-swizzled source), one barrier
// per K-tile, XCD-aware bijective block swizzle.
template<bool ADDC>
__global__ __launch_bounds__(512)
void mgemm(const u16* __restrict__ Ah, const u16* __restrict__ Al,
           const u16* __restrict__ Bh, const u16* __restrict__ Bl,
           const float* __restrict__ Cin, int ldcin,
           float* __restrict__ C, float* __restrict__ C2, int nsplit, int ldc,
           int K)
{
    __shared__ u16 lds[2][4][128][64];            // 128 KB, 2 buffers x {Ah,Al,Bh,Bl}
    const int tid = threadIdx.x;

    // ---- XCD-aware bijective swizzle (nwg % 8 == 0 for all our shapes)
    const int gx = gridDim.x;
    const int nwg = gx * gridDim.y;
    int id = blockIdx.y * gx + blockIdx.x;
    id = (id & 7) * (nwg >> 3) + (id >> 3);
    const int bm = (id / gx) * 128, bn = (id % gx) * 128;

    const int lane = tid & 63;
    const int w = tid >> 6, wr = w >> 2, wc = w & 3;

    // staging: lane -> (row = w*8 + (lane>>3) [+64*j], chunk = lane&7)
    // LDS stays linear; global source chunk pre-swizzled: gchk = chk ^ (row&7)
    const int r8 = lane >> 3, chk = lane & 7;
    const int gchk = chk ^ r8;                    // (w*8+r8)&7 == r8
    const u16* sp[4][2];
#pragma unroll
    for (int T = 0; T < 4; ++T) {
        const u16* base = T == 0 ? Ah : T == 1 ? Al : T == 2 ? Bh : Bl;
        const int g0 = (T < 2 ? bm : bn);
#pragma unroll
        for (int j = 0; j < 2; ++j)
            sp[T][j] = base + (size_t)(g0 + w * 8 + r8 + j * 64) * K + gchk * 8;
    }

    f32x4 acc[4][2];
#pragma unroll
    for (int i = 0; i < 4; ++i)
#pragma unroll
        for (int j = 0; j < 2; ++j)
            acc[i][j] = (f32x4){0.f, 0.f, 0.f, 0.f};

    const int nkt = K >> 6;

#define STAGE(b, kt)                                                          \
    {                                                                         \
        _Pragma("unroll")                                                     \
        for (int T = 0; T < 4; ++T)                                           \
            _Pragma("unroll")                                                 \
            for (int j = 0; j < 2; ++j)                                       \
                __builtin_amdgcn_global_load_lds(                             \
                    (const __attribute__((address_space(1))) unsigned int*)   \
                        (sp[T][j] + (size_t)(kt) * 64),                       \
                    (__attribute__((address_space(3))) unsigned int*)         \
                        &lds[b][T][j * 64 + w * 8][0],                        \
                    16, 0, 0);                                                \
    }

    STAGE(0, 0);
    int cur = 0;
    for (int kt = 0; kt < nkt; ++kt) {
        asm volatile("s_waitcnt vmcnt(0)" ::: "memory");
        __builtin_amdgcn_s_barrier();
        __builtin_amdgcn_sched_barrier(0);
        if (kt + 1 < nkt) STAGE(cur ^ 1, kt + 1);   // flies under compute
#pragma unroll
        for (int ks = 0; ks < 2; ++ks) {
            bf16x8 ah[4], al[4], bh[2], bl[2];
            const int kc = ks * 4 + (lane >> 4);
#pragma unroll
            for (int mi = 0; mi < 4; ++mi) {
                int row = wr * 64 + mi * 16 + (lane & 15);
                int rc = kc ^ (row & 7);
                ah[mi] = *(const bf16x8*)&lds[cur][0][row][rc * 8];
                al[mi] = *(const bf16x8*)&lds[cur][1][row][rc * 8];
            }
#pragma unroll
            for (int ni = 0; ni < 2; ++ni) {
                int col = wc * 32 + ni * 16 + (lane & 15);
                int rc = kc ^ (col & 7);
                bh[ni] = *(const bf16x8*)&lds[cur][2][col][rc * 8];
                bl[ni] = *(const bf16x8*)&lds[cur][3][col][rc * 8];
            }
#pragma unroll
            for (int mi = 0; mi < 4; ++mi)
#pragma unroll
                for (int ni = 0; ni < 2; ++ni) {
                    acc[mi][ni] = __builtin_amdgcn_mfma_f32_16x16x32_bf16(
                        ah[mi], bh[ni], acc[mi][ni], 0, 0, 0);
                    acc[mi][ni] = __builtin_amdgcn_mfma_f32_16x16x32_bf16(
                        ah[mi], bl[ni], acc[mi][ni], 0, 0, 0);
                    acc[mi][ni] = __builtin_amdgcn_mfma_f32_16x16x32_bf16(
                        al[mi], bh[ni], acc[mi][ni], 0, 0, 0);
                }
        }
        __builtin_amdgcn_sched_barrier(0);
        cur ^= 1;
    }
#undef STAGE

    // epilogue: C/D layout col = lane&15, row = (lane>>4)*4 + r
#pragma unroll
    for (int mi = 0; mi < 4; ++mi) {
        int row0 = bm + wr * 64 + mi * 16 + (lane >> 4) * 4;
#pragma unroll
        for (int ni = 0; ni < 2; ++ni) {
            int col = bn + wc * 32 + ni * 16 + (lane & 15);
            float* Cp = C; int cc = col;
            if (col >= nsplit) { Cp = C2; cc = col - nsplit; }
#pragma unroll
            for (int r = 0; r < 4; ++r) {
                float v = acc[mi][ni][r];
                if (ADDC) v += Cin[(size_t)(row0 + r) * ldcin + col];
                Cp[(size_t)(row0 + r) * ldc + cc] = v;
            }
        }
    }
}

// ---------------------------------------------------------------- SGEMM (fp32, small)
template<int BM, int BN, int BK, int TM, int TN, int ACT, bool BIAS, bool ADDC>
__global__ __launch_bounds__(256)
void sgemm(const float* __restrict__ A, int lda,
           const float* __restrict__ B, int ldb,
           const float* __restrict__ bias,
           const float* __restrict__ Cin, int ldcin,
           float* __restrict__ C, int ldc,
           int K)
{
    __shared__ float As[BK][BM];
    __shared__ float Bs[BK][BN];
    const int tid = threadIdx.x;
    const int bm = blockIdx.y * BM;
    const int bn = blockIdx.x * BN;

    const int AR = tid / (BK / 4);
    const int AC = (tid % (BK / 4)) * 4;
    const int BR = tid / (BN / 4);
    const int BC = (tid % (BN / 4)) * 4;
    const int tx = tid % (BN / TN);
    const int ty = tid / (BN / TN);

    float acc[TM][TN] = {};

    for (int k0 = 0; k0 < K; k0 += BK) {
        float4 av = *(const float4*)&A[(bm + AR) * lda + k0 + AC];
        float4 bv = *(const float4*)&B[(k0 + BR) * ldb + bn + BC];
        __syncthreads();
        As[AC + 0][AR] = av.x;
        As[AC + 1][AR] = av.y;
        As[AC + 2][AR] = av.z;
        As[AC + 3][AR] = av.w;
        *(float4*)&Bs[BR][BC] = bv;
        __syncthreads();
#pragma unroll
        for (int kk = 0; kk < BK; ++kk) {
            float a[TM], b[TN];
#pragma unroll
            for (int i = 0; i < TM; i += 4)
                *(float4*)&a[i] = *(const float4*)&As[kk][ty * TM + i];
#pragma unroll
            for (int j = 0; j < TN; j += 4)
                *(float4*)&b[j] = *(const float4*)&Bs[kk][tx * TN + j];
#pragma unroll
            for (int i = 0; i < TM; ++i)
#pragma unroll
                for (int j = 0; j < TN; ++j)
                    acc[i][j] = fmaf(a[i], b[j], acc[i][j]);
        }
    }

#pragma unroll
    for (int i = 0; i < TM; ++i) {
        int row = bm + ty * TM + i;
#pragma unroll
        for (int j = 0; j < TN; ++j) {
            int col = bn + tx * TN + j;
            float v = acc[i][j];
            if (BIAS) v += bias[col];
            if (ACT == 1) v = softplusf(v);
            if (ADDC) v += Cin[row * ldcin + col];
            C[row * ldc + col] = v;
        }
    }
}

// ---------------------------------------------------------------- conv + silu
__global__ __launch_bounds__(256)
void conv_kernel(const float* __restrict__ xi, const float* __restrict__ conv_w,
                 const float* __restrict__ conv_b, float* __restrict__ xc)
{
    int idx = blockIdx.x * 256 + threadIdx.x;      // [NTOK*DI)
    int d = idx & (DI - 1);
    int ct = idx >> 10;
    int t = ct & (LL - 1);
    float4 w = *(const float4*)&conv_w[d * 4];
    float acc = conv_b[d];
    if (t >= 3) acc = fmaf(xi[(ct - 3) * DI + d], w.x, acc);
    if (t >= 2) acc = fmaf(xi[(ct - 2) * DI + d], w.y, acc);
    if (t >= 1) acc = fmaf(xi[(ct - 1) * DI + d], w.z, acc);
    acc = fmaf(xi[ct * DI + d], w.w, acc);
    xc[idx] = siluf(acc);
}

// ---------------------------------------------------------------- scan S1
__global__ __launch_bounds__(256)
void scan1_kernel(const float* __restrict__ dtp, const float* __restrict__ xcp,
                  const float* __restrict__ dbc, const float* __restrict__ A_log,
                  float* __restrict__ hseg, float* __restrict__ Dsum)
{
    const int tid = threadIdx.x;
    int b = blockIdx.x;
    const int dblk = b & 3;
    const int seg  = (b >> 2) & (NSEG - 1);
    const int c    = b >> 6;
    const int d = dblk * 256 + tid;

    float A2[DS];
#pragma unroll
    for (int s = 0; s < DS; ++s)
        A2[s] = -__expf(A_log[d * DS + s]) * 1.44269504f;
    float h[DS] = {};
    float Dacc = 0.f;

    int idx  = (c * LL + seg * TSEG) * DI + d;
    int bidx = (c * LL + seg * TSEG) * 64 + 32;

    for (int t = 0; t < TSEG; ++t) {
        float dt = dtp[idx];
        float xc = xcp[idx];
        float4 Bq0 = *(const float4*)&dbc[bidx];
        float4 Bq1 = *(const float4*)&dbc[bidx + 4];
        float4 Bq2 = *(const float4*)&dbc[bidx + 8];
        float4 Bq3 = *(const float4*)&dbc[bidx + 12];
        Dacc += dt;
        float dtx = dt * xc;
#pragma unroll
        for (int qi = 0; qi < 4; ++qi) {
            float4 Bv = qi == 0 ? Bq0 : qi == 1 ? Bq1 : qi == 2 ? Bq2 : Bq3;
#pragma unroll
            for (int r = 0; r < 4; ++r) {
                int s = qi * 4 + r;
                float dA = fexp2(dt * A2[s]);
                h[s] = fmaf(dA, h[s], dtx * q4(Bv, r));
            }
        }
        idx += DI; bidx += 64;
    }

    int ho = ((c * NSEG + seg) * DI + d) * DS;
#pragma unroll
    for (int s = 0; s < DS; s += 4)
        *(float4*)&hseg[ho + s] = make_float4(h[s], h[s + 1], h[s + 2], h[s + 3]);
    Dsum[(c * NSEG + seg) * DI + d] = Dacc;
}

// ---------------------------------------------------------------- scan S2
__global__ __launch_bounds__(256)
void scan2_kernel(float* hseg, const float* __restrict__ Dsum,
                  const float* __restrict__ A_log)
{
    int g = blockIdx.x * 256 + threadIdx.x;      // (c*DI+d)*16 + s
    const int s  = g & 15;
    const int cd = g >> 4;
    const int d = cd & (DI - 1);
    const int c = cd >> 10;
    const float A2 = -__expf(A_log[d * DS + s]) * 1.44269504f;

    float h = 0.f;
#pragma unroll
    for (int k = 0; k < NSEG; ++k) {
        int o = ((c * NSEG + k) * DI + d) * DS + s;
        float he = hseg[o];
        float Dk = Dsum[(c * NSEG + k) * DI + d];
        hseg[o] = h;                              // h_in for segment k
        h = fmaf(fexp2(A2 * Dk), h, he);          // carry to k+1
    }
}

// ---------------------------------------------------------------- scan S3
__global__ __launch_bounds__(256)
void scan3_kernel(float* dty, const float* __restrict__ xcp,
                  const float* __restrict__ zp, const float* __restrict__ dbc,
                  const float* __restrict__ A_log, const float* __restrict__ Dp,
                  const float* __restrict__ hseg)
{
    const int tid = threadIdx.x;
    int b = blockIdx.x;
    const int dblk = b & 3;
    const int seg  = (b >> 2) & (NSEG - 1);
    const int c    = b >> 6;
    const int d = dblk * 256 + tid;

    float A2[DS];
#pragma unroll
    for (int s = 0; s < DS; ++s)
        A2[s] = -__expf(A_log[d * DS + s]) * 1.44269504f;
    const float Dpd = Dp[d];

    float h[DS];
    int ho = ((c * NSEG + seg) * DI + d) * DS;
#pragma unroll
    for (int s = 0; s < DS; s += 4) {
        float4 hv = *(const float4*)&hseg[ho + s];
        h[s] = hv.x; h[s + 1] = hv.y; h[s + 2] = hv.z; h[s + 3] = hv.w;
    }

    int idx  = (c * LL + seg * TSEG) * DI + d;
    int bidx = (c * LL + seg * TSEG) * 64 + 32;

    float ndt = dty[idx], nxc = xcp[idx], nz = zp[idx];

    for (int t = 0; t < TSEG; ++t) {
        float dt = ndt, xc = nxc, z = nz;
        if (t + 1 < TSEG) {
            ndt = dty[idx + DI]; nxc = xcp[idx + DI]; nz = zp[idx + DI];
        }
        float4 Bq0 = *(const float4*)&dbc[bidx];
        float4 Bq1 = *(const float4*)&dbc[bidx + 4];
        float4 Bq2 = *(const float4*)&dbc[bidx + 8];
        float4 Bq3 = *(const float4*)&dbc[bidx + 12];
        float4 Cq0 = *(const float4*)&dbc[bidx + 16];
        float4 Cq1 = *(const float4*)&dbc[bidx + 20];
        float4 Cq2 = *(const float4*)&dbc[bidx + 24];
        float4 Cq3 = *(const float4*)&dbc[bidx + 28];
        float dtx = dt * xc;
        float yt = 0.f;
#pragma unroll
        for (int qi = 0; qi < 4; ++qi) {
            float4 Bv = qi == 0 ? Bq0 : qi == 1 ? Bq1 : qi == 2 ? Bq2 : Bq3;
            float4 Cv = qi == 0 ? Cq0 : qi == 1 ? Cq1 : qi == 2 ? Cq2 : Cq3;
#pragma unroll
            for (int r = 0; r < 4; ++r) {
                int s = qi * 4 + r;
                float dA = fexp2(dt * A2[s]);
                h[s] = fmaf(dA, h[s], dtx * q4(Bv, r));
                yt = fmaf(h[s], q4(Cv, r), yt);
            }
        }
        dty[idx] = (yt + xc * Dpd) * siluf(z);
        idx += DI; bidx += 64;
    }
}

// ---------------------------------------------------------------- mean over L
__global__ __launch_bounds__(64)
void mean_kernel(const float* __restrict__ chunks, float* __restrict__ meanb)
{
    int j = blockIdx.x * 64 + threadIdx.x;
    int c = blockIdx.y;
    float s = 0.f;
    for (int t = 0; t < LL; ++t) s += chunks[(c * LL + t) * DM + j];
    meanb[c * DM + j] = s * (1.f / LL);
}

// ---------------------------------------------------------------- summaries
__global__ __launch_bounds__(256)
void summ_kernel(const float* __restrict__ meanb, const float* __restrict__ sum_w,
                 const float* __restrict__ sum_b, float* __restrict__ summ)
{
    int n = blockIdx.x * 256 + threadIdx.x;
    int c = blockIdx.y;
    float acc = sum_b[n];
    for (int k = 0; k < DM; ++k) acc = fmaf(meanb[c * DM + k], sum_w[k * DM + n], acc);
    summ[c * DM + n] = acc;
}

__global__ __launch_bounds__(256)
void kv_kernel(const float* __restrict__ summ, const float* __restrict__ wk,
               const float* __restrict__ wv, float* __restrict__ kb,
               float* __restrict__ vb)
{
    int n = blockIdx.x * 256 + threadIdx.x;
    int c = blockIdx.y;
    float ak = 0.f, av = 0.f;
    for (int k = 0; k < DM; ++k) {
        float s = summ[c * DM + k];
        ak = fmaf(s, wk[k * DM + n], ak);
        av = fmaf(s, wv[k * DM + n], av);
    }
    kb[c * DM + n] = ak;
    vb[c * DM + n] = av;
}

// ---------------------------------------------------------------- cross-attn
__global__ __launch_bounds__(128)
void attn_kernel(float* qv,                      // [NTOK, DM] q in / attnv out
                 const float* __restrict__ kb,   // [NC, DM]
                 const float* __restrict__ vb)   // [NC, DM]
{
    __shared__ float sq[DM];
    __shared__ float sAttn[NH][NC];
    const int ct = blockIdx.x;
    const int c = ct >> 10;
    const int tid = threadIdx.x;

    *(float4*)&sq[tid * 4] = *(const float4*)&qv[ct * DM + tid * 4];
    __syncthreads();

    const int h = tid >> 4, j = tid & 15;
    const float* kr = kb + j * DM + h * DH;
    const float* qr = sq + h * DH;
    float s = 0.f;
#pragma unroll
    for (int d0 = 0; d0 < DH; d0 += 4) {
        float4 k4 = *(const float4*)&kr[d0];
        float4 qv4 = *(const float4*)&qr[d0];
        s += qv4.x * k4.x + qv4.y * k4.y + qv4.z * k4.z + qv4.w * k4.w;
    }
    s *= 0.125f;                                  // 1/sqrt(64)
    if (j == c) s = -__builtin_inff();

    float m = s;
#pragma unroll
    for (int o = 1; o < 16; o <<= 1) m = fmaxf(m, __shfl_xor(m, o));
    float e = __expf(s - m);
    float sum = e;
#pragma unroll
    for (int o = 1; o < 16; o <<= 1) sum += __shfl_xor(sum, o);
    sAttn[h][j] = e / sum;
    __syncthreads();

#pragma unroll
    for (int r = 0; r < 4; ++r) {
        int o = r * 128 + tid;
        int h2 = o >> 6;
        float acc = 0.f;
#pragma unroll
        for (int jj = 0; jj < NC; ++jj)
            acc = fmaf(sAttn[h2][jj], vb[jj * DM + o], acc);
        qv[ct * DM + o] = acc;
    }
}

// ---------------------------------------------------------------- launch
extern "C" void kernel_launch(void* const* d_in, const int* in_sizes, int n_in,
                              void* d_out, int out_size, void* d_ws, size_t ws_size,
                              hipStream_t stream)
{
    const float* chunks   = (const float*)d_in[0];
    const float* in_proj  = (const float*)d_in[1];
    const float* conv_w   = (const float*)d_in[2];
    const float* conv_b   = (const float*)d_in[3];
    const float* x_proj   = (const float*)d_in[4];
    const float* dt_w     = (const float*)d_in[5];
    const float* dt_b     = (const float*)d_in[6];
    const float* A_log    = (const float*)d_in[7];
    const float* Dp       = (const float*)d_in[8];
    const float* out_proj = (const float*)d_in[9];
    const float* sum_w    = (const float*)d_in[10];
    const float* sum_b    = (const float*)d_in[11];
    const float* wq       = (const float*)d_in[12];
    const float* wk       = (const float*)d_in[13];
    const float* wv       = (const float*)d_in[14];
    const float* wo       = (const float*)d_in[15];
    float* out = (float*)d_out;

    // -------- workspace layout: identical footprint to R4 (~213 MB)
    float* ws   = (float*)d_ws;
    float* bufA = ws;                            // [NTOK,DI] xi -> dt -> y -> {tokH/L, avH/L}
    float* bufB = bufA + (size_t)NTOK * DI;      // [NTOK,DI] z -> q -> attnv
    float* bufC = bufB + (size_t)NTOK * DI;      // [NTOK,DI] {chH/L} -> xc -> {yH/L}
    float* dbc  = bufC + (size_t)NTOK * DI;      // [NTOK,64]
    float* meanb= dbc + (size_t)NTOK * 64;       // [16,512]
    float* summ = meanb + NC * DM;
    float* kb   = summ + NC * DM;
    float* vb   = kb + NC * DM;
    float* hseg = vb + NC * DM;                  // [NC,NSEG,DI,DS]; aliases ipT then {opT,wqT,woT}
    float* Dsum = hseg + (size_t)NC * NSEG * DI * DS;  // [NC,NSEG,DI]

    // u16 aliases (all within existing fp32 buffers; lifetimes verified)
    u16* chH  = (u16*)bufC;                      // [NTOK,DM]  dead after G1
    u16* chL  = chH + (size_t)NTOK * DM;
    u16* yH   = (u16*)bufC;                      // [NTOK,DI]  written after scan3 (xc dead)
    u16* yL   = yH + (size_t)NTOK * DI;          //  = 64 MB exactly (all of bufC)
    u16* tokH = (u16*)bufA;                      // [NTOK,DM]  written after G4 (y dead)
    u16* tokL = tokH + (size_t)NTOK * DM;
    u16* avH  = (u16*)bufA + (size_t)NTOK * DI;  // bufA second half
    u16* avL  = avH + (size_t)NTOK * DM;
    u16* ipTh = (u16*)hseg;                      // [2048,512] dead after G1; hseg written later
    u16* ipTl = ipTh + (size_t)2048 * 512;
    u16* opTh = (u16*)hseg;                      // written after scan3 (hseg dead)
    u16* opTl = opTh + (size_t)512 * 1024;
    u16* wqTh = opTl + (size_t)512 * 1024;
    u16* wqTl = wqTh + (size_t)512 * 512;
    u16* woTh = wqTl + (size_t)512 * 512;
    u16* woTl = woTh + (size_t)512 * 512;

    dim3 blk512(512), blk256(256), blk128(128), blk64(64);
    const int BIG = 1 << 30;

    // ---- split in_proj (into hseg region) + chunks (into bufC)
    splitT_kernel<<<dim3(2048 / 64, 512 / 64), blk256, 0, stream>>>(in_proj, ipTh, ipTl, 512, 2048);
    split_kernel<<<NTOK * DM / 4 / 256, blk256, 0, stream>>>(chunks, chH, chL, NTOK * DM / 4);
    // G1: [xi | z] = chunks @ in_proj  (M=16384, N=2048, K=512)
    mgemm<false><<<dim3(2048 / 128, NTOK / 128), blk512, 0, stream>>>(
        chH, chL, ipTh, ipTl, nullptr, 0, bufA, bufB, 1024, DI, DM);
    // conv + silu: xc -> bufC (overwrites chH/chL, dead)
    conv_kernel<<<NTOK * DI / 256, blk256, 0, stream>>>(bufA, conv_w, conv_b, bufC);
    // G2: dbc = xc @ x_proj (fp32, N=64)
    sgemm<64, 64, 16, 4, 4, 0, false, false><<<dim3(1, NTOK / 64), blk256, 0, stream>>>(
        bufC, DI, x_proj, 64, nullptr, nullptr, 0, dbc, 64, DI);
    // G3: dt = softplus(dbc[:, :32] @ dt_w + dt_b) -> bufA (xi dead)
    sgemm<128, 128, 8, 8, 8, 1, true, false><<<dim3(DI / 128, NTOK / 128), blk256, 0, stream>>>(
        dbc, 64, dt_w, DI, dt_b, nullptr, 0, bufA, DI, 32);
    // scan: 3-phase segmented; scan1 overwrites ipT region with hseg (ipT dead)
    scan1_kernel<<<NC * NSEG * (DI / 256), blk256, 0, stream>>>(bufA, bufC, dbc, A_log, hseg, Dsum);
    scan2_kernel<<<NC * DI * DS / 256, blk256, 0, stream>>>(hseg, Dsum, A_log);
    scan3_kernel<<<NC * NSEG * (DI / 256), blk256, 0, stream>>>(bufA, bufC, bufB, dbc, A_log, Dp, hseg);
    // split y (bufA) -> yH/yL in bufC (xc dead)
    split_kernel<<<NTOK * DI / 4 / 256, blk256, 0, stream>>>(bufA, yH, yL, NTOK * DI / 4);
    // split remaining weights into hseg region (hseg dead after scan3)
    splitT_kernel<<<dim3(512 / 64, 1024 / 64), blk256, 0, stream>>>(out_proj, opTh, opTl, 1024, 512);
    splitT_kernel<<<dim3(512 / 64, 512 / 64), blk256, 0, stream>>>(wq, wqTh, wqTl, 512, 512);
    splitT_kernel<<<dim3(512 / 64, 512 / 64), blk256, 0, stream>>>(wo, woTh, woTl, 512, 512);
    // G4: tok = y @ out_proj -> d_out used as scratch (fully overwritten)
    mgemm<false><<<dim3(DM / 128, NTOK / 128), blk512, 0, stream>>>(
        yH, yL, opTh, opTl, nullptr, 0, out, nullptr, BIG, DM, DI);
    // summaries
    mean_kernel<<<dim3(DM / 64, NC), blk64, 0, stream>>>(chunks, meanb);
    summ_kernel<<<dim3(2, NC), blk256, 0, stream>>>(meanb, sum_w, sum_b, summ);
    kv_kernel<<<dim3(2, NC), blk256, 0, stream>>>(summ, wk, wv, kb, vb);
    // split tok (d_out) -> tokH/tokL in bufA (y dead)
    split_kernel<<<NTOK * DM / 4 / 256, blk256, 0, stream>>>(out, tokH, tokL, NTOK * DM / 4);
    // G5: q = tok @ wq -> bufB (z dead)
    mgemm<false><<<dim3(DM / 128, NTOK / 128), blk512, 0, stream>>>(
        tokH, tokL, wqTh, wqTl, nullptr, 0, bufB, nullptr, BIG, DM, DM);
    // attn: in-place on bufB rows
    attn_kernel<<<NTOK, blk128, 0, stream>>>(bufB, kb, vb);
    // split attnv (bufB) -> avH/avL in bufA second half (tokH/tokL dead after G5)
    split_kernel<<<NTOK * DM / 4 / 256, blk256, 0, stream>>>(bufB, avH, avL, NTOK * DM / 4);
    // G6: out = tok + attnv @ wo  (Cin = d_out read-then-write, same thread)
    mgemm<true><<<dim3(DM / 128, NTOK / 128), blk512, 0, stream>>>(
        avH, avL, woTh, woTl, out, DM, out, nullptr, BIG, DM, DM);
}

// Round 8
// 869.430 us; speedup vs baseline: 2.0303x; 1.0274x over previous
//
#include <hip/hip_runtime.h>

// ---------------------------------------------------------------- constants
constexpr int NC  = 16;    // n_chunks
constexpr int LL  = 1024;  // chunk len
constexpr int DM  = 512;   // d_model
constexpr int DI  = 1024;  // d_inner
constexpr int DS  = 16;    // d_state
constexpr int NH  = 8;     // heads
constexpr int DH  = 64;    // head dim
constexpr int NTOK = NC * LL;  // 16384
constexpr int NSEG = 16;   // scan segments
constexpr int TSEG = LL / NSEG;  // 64
constexpr int NF  = 1152;  // fused dbc GEMM padded N (1024 dt + 32 bc + 96 pad)

typedef unsigned short u16;
typedef __attribute__((ext_vector_type(8))) short bf16x8;
typedef __attribute__((ext_vector_type(4))) float f32x4;

__device__ __forceinline__ float softplusf(float x) {
    return x > 20.f ? x : log1pf(__expf(x));
}
__device__ __forceinline__ float siluf(float x) {
    return x / (1.f + __expf(-x));
}
__device__ __forceinline__ float fexp2(float x) {
    return __builtin_amdgcn_exp2f(x);             // v_exp_f32
}
__device__ __forceinline__ float q4(const float4& v, int r) {
    return r == 0 ? v.x : r == 1 ? v.y : r == 2 ? v.z : v.w;  // r compile-time
}
__device__ __forceinline__ u16 f2bf(float f) {    // RNE fp32 -> bf16 bits
    union { float f; unsigned u; } v; v.f = f;
    unsigned u = v.u;
    return (u16)((u + 0x7FFFu + ((u >> 16) & 1u)) >> 16);
}
__device__ __forceinline__ float bf2f(u16 h) {
    union { unsigned u; float f; } v; v.u = (unsigned)h << 16;
    return v.f;
}

// ---------------------------------------------------------------- split (linear)
__global__ __launch_bounds__(256)
void split_kernel(const float* __restrict__ in, u16* __restrict__ hi,
                  u16* __restrict__ lo, int n4)
{
    int i = blockIdx.x * 256 + threadIdx.x;
    if (i >= n4) return;
    float4 v = ((const float4*)in)[i];
    ushort4 h, l;
    h.x = f2bf(v.x); l.x = f2bf(v.x - bf2f(h.x));
    h.y = f2bf(v.y); l.y = f2bf(v.y - bf2f(h.y));
    h.z = f2bf(v.z); l.z = f2bf(v.z - bf2f(h.z));
    h.w = f2bf(v.w); l.w = f2bf(v.w - bf2f(h.w));
    ((ushort4*)hi)[i] = h;
    ((ushort4*)lo)[i] = l;
}

// ---------------------------------------------------------------- splitT
// weights fp32 [K][N] -> bf16 hi/lo [N][K] via LDS 64x64 tile transpose
__global__ __launch_bounds__(256)
void splitT_kernel(const float* __restrict__ in, u16* __restrict__ hi,
                   u16* __restrict__ lo, int K, int N)
{
    __shared__ float tile[64][65];
    const int k0 = blockIdx.y * 64, n0 = blockIdx.x * 64;
    const int tr = threadIdx.x >> 6, tc = threadIdx.x & 63;
#pragma unroll
    for (int i = 0; i < 16; ++i) {
        int r = tr * 16 + i;
        tile[r][tc] = in[(size_t)(k0 + r) * N + n0 + tc];
    }
    __syncthreads();
#pragma unroll
    for (int i = 0; i < 16; ++i) {
        int r = tr * 16 + i;
        float v = tile[tc][r];                    // in[k0+tc][n0+r]
        u16 h = f2bf(v);
        u16 l = f2bf(v - bf2f(h));
        size_t o = (size_t)(n0 + r) * K + k0 + tc;
        hi[o] = h;
        lo[o] = l;
    }
}

// ---------------------------------------------------------------- fused weight
// WfT[n][k] (bf16 hi/lo), n in [0,1056):
//   n < 1024 : (x_proj[:, :32] @ dt_w)[k][n]
//   else     : x_proj[k][32 + n - 1024]         (B|C columns)
__global__ __launch_bounds__(256)
void wfused_kernel(const float* __restrict__ x_proj,   // [1024][64]
                   const float* __restrict__ dt_w,     // [32][1024]
                   u16* __restrict__ wh, u16* __restrict__ wl)
{
    int idx = blockIdx.x * 256 + threadIdx.x;     // n*1024 + k, n in [0,1056)
    int k = idx & 1023;
    int n = idx >> 10;
    float v;
    if (n < 1024) {
        v = 0.f;
#pragma unroll
        for (int r = 0; r < 32; ++r)
            v = fmaf(x_proj[k * 64 + r], dt_w[r * 1024 + n], v);
    } else {
        v = x_proj[k * 64 + 32 + (n - 1024)];
    }
    u16 h = f2bf(v);
    wh[idx] = h;
    wl[idx] = f2bf(v - bf2f(h));
}

// ---------------------------------------------------------------- MFMA GEMM (bf16x3)
// C = Ah*Bh + Ah*Bl + Al*Bh; A split [M][K], B split [N][K].
// MODE 0: plain store. MODE 1: col<nsplit -> C else C2 (same ldc).
// MODE 2: += Cin. MODE 3: col<nsplit -> softplus(+bias) into C;
//         col in [nsplit, nsplit+32) -> C2 (ldc2); else dropped.
// 128x128 tile, BK=64, 512 thr (8 waves 2x4), global_load_lds double-buffered,
// linear LDS dest + pre-swizzled source, XCD-aware bijective block swizzle.
template<int MODE>
__global__ __launch_bounds__(512)
void mgemm(const u16* __restrict__ Ah, const u16* __restrict__ Al,
           const u16* __restrict__ Bh, const u16* __restrict__ Bl,
           const float* __restrict__ Cin, int ldcin,
           float* __restrict__ C, float* __restrict__ C2, int nsplit, int ldc,
           int ldc2, const float* __restrict__ bias, int K)
{
    __shared__ u16 lds[2][4][128][64];            // 128 KB
    const int tid = threadIdx.x;

    const int gx = gridDim.x;
    const int nwg = gx * gridDim.y;
    int id = blockIdx.y * gx + blockIdx.x;
    id = (id & 7) * (nwg >> 3) + (id >> 3);
    const int bm = (id / gx) * 128, bn = (id % gx) * 128;

    const int lane = tid & 63;
    const int w = tid >> 6, wr = w >> 2, wc = w & 3;

    const int r8 = lane >> 3, chk = lane & 7;
    const int gchk = chk ^ r8;
    const u16* sp[4][2];
#pragma unroll
    for (int T = 0; T < 4; ++T) {
        const u16* base = T == 0 ? Ah : T == 1 ? Al : T == 2 ? Bh : Bl;
        const int g0 = (T < 2 ? bm : bn);
#pragma unroll
        for (int j = 0; j < 2; ++j)
            sp[T][j] = base + (size_t)(g0 + w * 8 + r8 + j * 64) * K + gchk * 8;
    }

    f32x4 acc[4][2];
#pragma unroll
    for (int i = 0; i < 4; ++i)
#pragma unroll
        for (int j = 0; j < 2; ++j)
            acc[i][j] = (f32x4){0.f, 0.f, 0.f, 0.f};

    const int nkt = K >> 6;

#define STAGE(b, kt)                                                          \
    {                                                                         \
        _Pragma("unroll")                                                     \
        for (int T = 0; T < 4; ++T)                                           \
            _Pragma("unroll")                                                 \
            for (int j = 0; j < 2; ++j)                                       \
                __builtin_amdgcn_global_load_lds(                             \
                    (const __attribute__((address_space(1))) unsigned int*)   \
                        (sp[T][j] + (size_t)(kt) * 64),                       \
                    (__attribute__((address_space(3))) unsigned int*)         \
                        &lds[b][T][j * 64 + w * 8][0],                        \
                    16, 0, 0);                                                \
    }

    STAGE(0, 0);
    int cur = 0;
    for (int kt = 0; kt < nkt; ++kt) {
        asm volatile("s_waitcnt vmcnt(0)" ::: "memory");
        __builtin_amdgcn_s_barrier();
        __builtin_amdgcn_sched_barrier(0);
        if (kt + 1 < nkt) STAGE(cur ^ 1, kt + 1);   // flies under compute
#pragma unroll
        for (int ks = 0; ks < 2; ++ks) {
            bf16x8 ah[4], al[4], bh[2], bl[2];
            const int kc = ks * 4 + (lane >> 4);
#pragma unroll
            for (int mi = 0; mi < 4; ++mi) {
                int row = wr * 64 + mi * 16 + (lane & 15);
                int rc = kc ^ (row & 7);
                ah[mi] = *(const bf16x8*)&lds[cur][0][row][rc * 8];
                al[mi] = *(const bf16x8*)&lds[cur][1][row][rc * 8];
            }
#pragma unroll
            for (int ni = 0; ni < 2; ++ni) {
                int col = wc * 32 + ni * 16 + (lane & 15);
                int rc = kc ^ (col & 7);
                bh[ni] = *(const bf16x8*)&lds[cur][2][col][rc * 8];
                bl[ni] = *(const bf16x8*)&lds[cur][3][col][rc * 8];
            }
#pragma unroll
            for (int mi = 0; mi < 4; ++mi)
#pragma unroll
                for (int ni = 0; ni < 2; ++ni) {
                    acc[mi][ni] = __builtin_amdgcn_mfma_f32_16x16x32_bf16(
                        ah[mi], bh[ni], acc[mi][ni], 0, 0, 0);
                    acc[mi][ni] = __builtin_amdgcn_mfma_f32_16x16x32_bf16(
                        ah[mi], bl[ni], acc[mi][ni], 0, 0, 0);
                    acc[mi][ni] = __builtin_amdgcn_mfma_f32_16x16x32_bf16(
                        al[mi], bh[ni], acc[mi][ni], 0, 0, 0);
                }
        }
        __builtin_amdgcn_sched_barrier(0);
        cur ^= 1;
    }
#undef STAGE

    // epilogue: C/D layout col = lane&15, row = (lane>>4)*4 + r
#pragma unroll
    for (int mi = 0; mi < 4; ++mi) {
        int row0 = bm + wr * 64 + mi * 16 + (lane >> 4) * 4;
#pragma unroll
        for (int ni = 0; ni < 2; ++ni) {
            int col = bn + wc * 32 + ni * 16 + (lane & 15);
            if (MODE == 3) {
                if (col < nsplit) {
#pragma unroll
                    for (int r = 0; r < 4; ++r)
                        C[(size_t)(row0 + r) * ldc + col] =
                            softplusf(acc[mi][ni][r] + bias[col]);
                } else if (col < nsplit + 32) {
#pragma unroll
                    for (int r = 0; r < 4; ++r)
                        C2[(size_t)(row0 + r) * ldc2 + (col - nsplit)] =
                            acc[mi][ni][r];
                }
            } else {
                float* Cp = C; int cc = col;
                if (MODE == 1 && col >= nsplit) { Cp = C2; cc = col - nsplit; }
#pragma unroll
                for (int r = 0; r < 4; ++r) {
                    float v = acc[mi][ni][r];
                    if (MODE == 2) v += Cin[(size_t)(row0 + r) * ldcin + col];
                    Cp[(size_t)(row0 + r) * ldc + cc] = v;
                }
            }
        }
    }
}

// ---------------------------------------------------------------- conv + silu -> bf16 hi/lo
__global__ __launch_bounds__(256)
void conv_kernel(const float* __restrict__ xi, const float* __restrict__ conv_w,
                 const float* __restrict__ conv_b,
                 u16* __restrict__ xcH, u16* __restrict__ xcL)
{
    int idx = blockIdx.x * 256 + threadIdx.x;      // [NTOK*DI)
    int d = idx & (DI - 1);
    int ct = idx >> 10;
    int t = ct & (LL - 1);
    float4 w = *(const float4*)&conv_w[d * 4];
    float acc = conv_b[d];
    if (t >= 3) acc = fmaf(xi[(ct - 3) * DI + d], w.x, acc);
    if (t >= 2) acc = fmaf(xi[(ct - 2) * DI + d], w.y, acc);
    if (t >= 1) acc = fmaf(xi[(ct - 1) * DI + d], w.z, acc);
    acc = fmaf(xi[ct * DI + d], w.w, acc);
    float v = siluf(acc);
    u16 h = f2bf(v);
    xcH[idx] = h;
    xcL[idx] = f2bf(v - bf2f(h));
}

// ---------------------------------------------------------------- scan S1
// bc layout: [NTOK][32], B = cols 0..15, C = cols 16..31
__global__ __launch_bounds__(256)
void scan1_kernel(const float* __restrict__ dtp,
                  const u16* __restrict__ xcH, const u16* __restrict__ xcL,
                  const float* __restrict__ bc, const float* __restrict__ A_log,
                  float* __restrict__ hseg, float* __restrict__ Dsum)
{
    const int tid = threadIdx.x;
    int b = blockIdx.x;
    const int dblk = b & 3;
    const int seg  = (b >> 2) & (NSEG - 1);
    const int c    = b >> 6;
    const int d = dblk * 256 + tid;

    float A2[DS];
#pragma unroll
    for (int s = 0; s < DS; ++s)
        A2[s] = -__expf(A_log[d * DS + s]) * 1.44269504f;
    float h[DS] = {};
    float Dacc = 0.f;

    int idx  = (c * LL + seg * TSEG) * DI + d;
    int bidx = (c * LL + seg * TSEG) * 32;

    for (int t = 0; t < TSEG; ++t) {
        float dt = dtp[idx];
        float xc = bf2f(xcH[idx]) + bf2f(xcL[idx]);
        float4 Bq0 = *(const float4*)&bc[bidx];
        float4 Bq1 = *(const float4*)&bc[bidx + 4];
        float4 Bq2 = *(const float4*)&bc[bidx + 8];
        float4 Bq3 = *(const float4*)&bc[bidx + 12];
        Dacc += dt;
        float dtx = dt * xc;
#pragma unroll
        for (int qi = 0; qi < 4; ++qi) {
            float4 Bv = qi == 0 ? Bq0 : qi == 1 ? Bq1 : qi == 2 ? Bq2 : Bq3;
#pragma unroll
            for (int r = 0; r < 4; ++r) {
                int s = qi * 4 + r;
                float dA = fexp2(dt * A2[s]);
                h[s] = fmaf(dA, h[s], dtx * q4(Bv, r));
            }
        }
        idx += DI; bidx += 32;
    }

    int ho = ((c * NSEG + seg) * DI + d) * DS;
#pragma unroll
    for (int s = 0; s < DS; s += 4)
        *(float4*)&hseg[ho + s] = make_float4(h[s], h[s + 1], h[s + 2], h[s + 3]);
    Dsum[(c * NSEG + seg) * DI + d] = Dacc;
}

// ---------------------------------------------------------------- scan S2
__global__ __launch_bounds__(256)
void scan2_kernel(float* hseg, const float* __restrict__ Dsum,
                  const float* __restrict__ A_log)
{
    int g = blockIdx.x * 256 + threadIdx.x;      // (c*DI+d)*16 + s
    const int s  = g & 15;
    const int cd = g >> 4;
    const int d = cd & (DI - 1);
    const int c = cd >> 10;
    const float A2 = -__expf(A_log[d * DS + s]) * 1.44269504f;

    float h = 0.f;
#pragma unroll
    for (int k = 0; k < NSEG; ++k) {
        int o = ((c * NSEG + k) * DI + d) * DS + s;
        float he = hseg[o];
        float Dk = Dsum[(c * NSEG + k) * DI + d];
        hseg[o] = h;                              // h_in for segment k
        h = fmaf(fexp2(A2 * Dk), h, he);          // carry to k+1
    }
}

// ---------------------------------------------------------------- scan S3
__global__ __launch_bounds__(256)
void scan3_kernel(float* dty,
                  const u16* __restrict__ xcH, const u16* __restrict__ xcL,
                  const float* __restrict__ zp, const float* __restrict__ bc,
                  const float* __restrict__ A_log, const float* __restrict__ Dp,
                  const float* __restrict__ hseg)
{
    const int tid = threadIdx.x;
    int b = blockIdx.x;
    const int dblk = b & 3;
    const int seg  = (b >> 2) & (NSEG - 1);
    const int c    = b >> 6;
    const int d = dblk * 256 + tid;

    float A2[DS];
#pragma unroll
    for (int s = 0; s < DS; ++s)
        A2[s] = -__expf(A_log[d * DS + s]) * 1.44269504f;
    const float Dpd = Dp[d];

    float h[DS];
    int ho = ((c * NSEG + seg) * DI + d) * DS;
#pragma unroll
    for (int s = 0; s < DS; s += 4) {
        float4 hv = *(const float4*)&hseg[ho + s];
        h[s] = hv.x; h[s + 1] = hv.y; h[s + 2] = hv.z; h[s + 3] = hv.w;
    }

    int idx  = (c * LL + seg * TSEG) * DI + d;
    int bidx = (c * LL + seg * TSEG) * 32;

    float ndt = dty[idx];
    float nxc = bf2f(xcH[idx]) + bf2f(xcL[idx]);
    float nz = zp[idx];

    for (int t = 0; t < TSEG; ++t) {
        float dt = ndt, xc = nxc, z = nz;
        if (t + 1 < TSEG) {
            ndt = dty[idx + DI];
            nxc = bf2f(xcH[idx + DI]) + bf2f(xcL[idx + DI]);
            nz = zp[idx + DI];
        }
        float4 Bq0 = *(const float4*)&bc[bidx];
        float4 Bq1 = *(const float4*)&bc[bidx + 4];
        float4 Bq2 = *(const float4*)&bc[bidx + 8];
        float4 Bq3 = *(const float4*)&bc[bidx + 12];
        float4 Cq0 = *(const float4*)&bc[bidx + 16];
        float4 Cq1 = *(const float4*)&bc[bidx + 20];
        float4 Cq2 = *(const float4*)&bc[bidx + 24];
        float4 Cq3 = *(const float4*)&bc[bidx + 28];
        float dtx = dt * xc;
        float yt = 0.f;
#pragma unroll
        for (int qi = 0; qi < 4; ++qi) {
            float4 Bv = qi == 0 ? Bq0 : qi == 1 ? Bq1 : qi == 2 ? Bq2 : Bq3;
            float4 Cv = qi == 0 ? Cq0 : qi == 1 ? Cq1 : qi == 2 ? Cq2 : Cq3;
#pragma unroll
            for (int r = 0; r < 4; ++r) {
                int s = qi * 4 + r;
                float dA = fexp2(dt * A2[s]);
                h[s] = fmaf(dA, h[s], dtx * q4(Bv, r));
                yt = fmaf(h[s], q4(Cv, r), yt);
            }
        }
        dty[idx] = (yt + xc * Dpd) * siluf(z);
        idx += DI; bidx += 32;
    }
}

// ---------------------------------------------------------------- mean over L
__global__ __launch_bounds__(64)
void mean_kernel(const float* __restrict__ chunks, float* __restrict__ meanb)
{
    int j = blockIdx.x * 64 + threadIdx.x;
    int c = blockIdx.y;
    float s = 0.f;
    for (int t = 0; t < LL; ++t) s += chunks[(c * LL + t) * DM + j];
    meanb[c * DM + j] = s * (1.f / LL);
}

// ---------------------------------------------------------------- summaries
__global__ __launch_bounds__(256)
void summ_kernel(const float* __restrict__ meanb, const float* __restrict__ sum_w,
                 const float* __restrict__ sum_b, float* __restrict__ summ)
{
    int n = blockIdx.x * 256 + threadIdx.x;
    int c = blockIdx.y;
    float acc = sum_b[n];
    for (int k = 0; k < DM; ++k) acc = fmaf(meanb[c * DM + k], sum_w[k * DM + n], acc);
    summ[c * DM + n] = acc;
}

__global__ __launch_bounds__(256)
void kv_kernel(const float* __restrict__ summ, const float* __restrict__ wk,
               const float* __restrict__ wv, float* __restrict__ kb,
               float* __restrict__ vb)
{
    int n = blockIdx.x * 256 + threadIdx.x;
    int c = blockIdx.y;
    float ak = 0.f, av = 0.f;
    for (int k = 0; k < DM; ++k) {
        float s = summ[c * DM + k];
        ak = fmaf(s, wk[k * DM + n], ak);
        av = fmaf(s, wv[k * DM + n], av);
    }
    kb[c * DM + n] = ak;
    vb[c * DM + n] = av;
}

// ---------------------------------------------------------------- cross-attn
__global__ __launch_bounds__(128)
void attn_kernel(float* qv,                      // [NTOK, DM] q in / attnv out
                 const float* __restrict__ kb,   // [NC, DM]
                 const float* __restrict__ vb)   // [NC, DM]
{
    __shared__ float sq[DM];
    __shared__ float sAttn[NH][NC];
    const int ct = blockIdx.x;
    const int c = ct >> 10;
    const int tid = threadIdx.x;

    *(float4*)&sq[tid * 4] = *(const float4*)&qv[ct * DM + tid * 4];
    __syncthreads();

    const int h = tid >> 4, j = tid & 15;
    const float* kr = kb + j * DM + h * DH;
    const float* qr = sq + h * DH;
    float s = 0.f;
#pragma unroll
    for (int d0 = 0; d0 < DH; d0 += 4) {
        float4 k4 = *(const float4*)&kr[d0];
        float4 qv4 = *(const float4*)&qr[d0];
        s += qv4.x * k4.x + qv4.y * k4.y + qv4.z * k4.z + qv4.w * k4.w;
    }
    s *= 0.125f;                                  // 1/sqrt(64)
    if (j == c) s = -__builtin_inff();

    float m = s;
#pragma unroll
    for (int o = 1; o < 16; o <<= 1) m = fmaxf(m, __shfl_xor(m, o));
    float e = __expf(s - m);
    float sum = e;
#pragma unroll
    for (int o = 1; o < 16; o <<= 1) sum += __shfl_xor(sum, o);
    sAttn[h][j] = e / sum;
    __syncthreads();

#pragma unroll
    for (int r = 0; r < 4; ++r) {
        int o = r * 128 + tid;
        int h2 = o >> 6;
        float acc = 0.f;
#pragma unroll
        for (int jj = 0; jj < NC; ++jj)
            acc = fmaf(sAttn[h2][jj], vb[jj * DM + o], acc);
        qv[ct * DM + o] = acc;
    }
}

// ---------------------------------------------------------------- launch
extern "C" void kernel_launch(void* const* d_in, const int* in_sizes, int n_in,
                              void* d_out, int out_size, void* d_ws, size_t ws_size,
                              hipStream_t stream)
{
    const float* chunks   = (const float*)d_in[0];
    const float* in_proj  = (const float*)d_in[1];
    const float* conv_w   = (const float*)d_in[2];
    const float* conv_b   = (const float*)d_in[3];
    const float* x_proj   = (const float*)d_in[4];
    const float* dt_w     = (const float*)d_in[5];
    const float* dt_b     = (const float*)d_in[6];
    const float* A_log    = (const float*)d_in[7];
    const float* Dp       = (const float*)d_in[8];
    const float* out_proj = (const float*)d_in[9];
    const float* sum_w    = (const float*)d_in[10];
    const float* sum_b    = (const float*)d_in[11];
    const float* wq       = (const float*)d_in[12];
    const float* wk       = (const float*)d_in[13];
    const float* wv       = (const float*)d_in[14];
    const float* wo       = (const float*)d_in[15];
    float* out = (float*)d_out;

    // -------- workspace layout: same ~214 MB footprint as R7
    float* ws   = (float*)d_ws;
    float* bufA = ws;                            // [NTOK,DI] xi -> dt -> y -> {tokH/L, avH/L}
    float* bufB = bufA + (size_t)NTOK * DI;      // [NTOK,DI] z -> q -> attnv
    float* bufC = bufB + (size_t)NTOK * DI;      // [NTOK,DI] {chH/L} -> {xcH/L} -> {yH/L}
    float* dbc  = bufC + (size_t)NTOK * DI;      // [NTOK,32] bc (B|C)
    float* meanb= dbc + (size_t)NTOK * 64;       // [16,512]
    float* summ = meanb + NC * DM;
    float* kb   = summ + NC * DM;
    float* vb   = kb + NC * DM;
    float* hseg = vb + NC * DM;                  // [NC,NSEG,DI,DS] 16.8MB; aliases ipT+WfT then {opT,wqT,woT}
    float* Dsum = hseg + (size_t)NC * NSEG * DI * DS;  // [NC,NSEG,DI]

    // u16 aliases (lifetimes verified)
    u16* chH  = (u16*)bufC;                      // [NTOK,DM] dead after G1
    u16* chL  = chH + (size_t)NTOK * DM;
    u16* xcH  = (u16*)bufC;                      // [NTOK,DI] conv output (overwrites chH/L)
    u16* xcL  = xcH + (size_t)NTOK * DI;
    u16* yH   = (u16*)bufC;                      // [NTOK,DI] written after scan3 (xc dead)
    u16* yL   = yH + (size_t)NTOK * DI;
    u16* tokH = (u16*)bufA;                      // [NTOK,DM] written after G4 (y dead)
    u16* tokL = tokH + (size_t)NTOK * DM;
    u16* avH  = (u16*)bufA + (size_t)NTOK * DI;  // bufA second half
    u16* avL  = avH + (size_t)NTOK * DM;
    u16* ipTh = (u16*)hseg;                      // [2048,512] dead after G1
    u16* ipTl = ipTh + (size_t)2048 * 512;
    u16* WfTh = ipTl + (size_t)2048 * 512;       // [NF,1024] fused weight (rows 0..1055 valid)
    u16* WfTl = WfTh + (size_t)NF * 1024;        // ends at ~8.9MB < 16.8MB region
    u16* opTh = (u16*)hseg;                      // written after scan3 (hseg dead)
    u16* opTl = opTh + (size_t)512 * 1024;
    u16* wqTh = opTl + (size_t)512 * 1024;
    u16* wqTl = wqTh + (size_t)512 * 512;
    u16* woTh = wqTl + (size_t)512 * 512;
    u16* woTl = woTh + (size_t)512 * 512;

    dim3 blk512(512), blk256(256), blk128(128), blk64(64);
    const int BIG = 1 << 30;

    // ---- weight prep + input split
    splitT_kernel<<<dim3(2048 / 64, 512 / 64), blk256, 0, stream>>>(in_proj, ipTh, ipTl, 512, 2048);
    wfused_kernel<<<1056 * 1024 / 256, blk256, 0, stream>>>(x_proj, dt_w, WfTh, WfTl);
    split_kernel<<<NTOK * DM / 4 / 256, blk256, 0, stream>>>(chunks, chH, chL, NTOK * DM / 4);
    // G1: [xi | z] = chunks @ in_proj  (M=16384, N=2048, K=512)
    mgemm<1><<<dim3(2048 / 128, NTOK / 128), blk512, 0, stream>>>(
        chH, chL, ipTh, ipTl, nullptr, 0, bufA, bufB, 1024, DI, DI, nullptr, DM);
    // conv + silu -> xcH/xcL (bufC; chH/L dead)
    conv_kernel<<<NTOK * DI / 256, blk256, 0, stream>>>(bufA, conv_w, conv_b, xcH, xcL);
    // fused dbc GEMM: dt = softplus(xc@Wdt + dt_b) -> bufA; B|C -> dbc
    mgemm<3><<<dim3(NF / 128, NTOK / 128), blk512, 0, stream>>>(
        xcH, xcL, WfTh, WfTl, nullptr, 0, bufA, dbc, 1024, DI, 32, dt_b, DI);
    // scan: 3-phase segmented (scan1 overwrites ipT/WfT with hseg — both dead)
    scan1_kernel<<<NC * NSEG * (DI / 256), blk256, 0, stream>>>(bufA, xcH, xcL, dbc, A_log, hseg, Dsum);
    scan2_kernel<<<NC * DI * DS / 256, blk256, 0, stream>>>(hseg, Dsum, A_log);
    scan3_kernel<<<NC * NSEG * (DI / 256), blk256, 0, stream>>>(bufA, xcH, xcL, bufB, dbc, A_log, Dp, hseg);
    // split y (bufA) -> yH/yL in bufC (xc dead)
    split_kernel<<<NTOK * DI / 4 / 256, blk256, 0, stream>>>(bufA, yH, yL, NTOK * DI / 4);
    // split remaining weights into hseg region (hseg dead after scan3)
    splitT_kernel<<<dim3(512 / 64, 1024 / 64), blk256, 0, stream>>>(out_proj, opTh, opTl, 1024, 512);
    splitT_kernel<<<dim3(512 / 64, 512 / 64), blk256, 0, stream>>>(wq, wqTh, wqTl, 512, 512);
    splitT_kernel<<<dim3(512 / 64, 512 / 64), blk256, 0, stream>>>(wo, woTh, woTl, 512, 512);
    // G4: tok = y @ out_proj -> d_out used as scratch (fully overwritten)
    mgemm<0><<<dim3(DM / 128, NTOK / 128), blk512, 0, stream>>>(
        yH, yL, opTh, opTl, nullptr, 0, out, nullptr, BIG, DM, 0, nullptr, DI);
    // summaries
    mean_kernel<<<dim3(DM / 64, NC), blk64, 0, stream>>>(chunks, meanb);
    summ_kernel<<<dim3(2, NC), blk256, 0, stream>>>(meanb, sum_w, sum_b, summ);
    kv_kernel<<<dim3(2, NC), blk256, 0, stream>>>(summ, wk, wv, kb, vb);
    // split tok (d_out) -> tokH/tokL in bufA (y dead)
    split_kernel<<<NTOK * DM / 4 / 256, blk256, 0, stream>>>(out, tokH, tokL, NTOK * DM / 4);
    // G5: q = tok @ wq -> bufB (z dead)
    mgemm<0><<<dim3(DM / 128, NTOK / 128), blk512, 0, stream>>>(
        tokH, tokL, wqTh, wqTl, nullptr, 0, bufB, nullptr, BIG, DM, 0, nullptr, DM);
    // attn: in-place on bufB rows
    attn_kernel<<<NTOK, blk128, 0, stream>>>(bufB, kb, vb);
    // split attnv (bufB) -> avH/avL (bufA second half; tok split dead after G5)
    split_kernel<<<NTOK * DM / 4 / 256, blk256, 0, stream>>>(bufB, avH, avL, NTOK * DM / 4);
    // G6: out = tok + attnv @ wo  (Cin = d_out read-then-write, same thread)
    mgemm<2><<<dim3(DM / 128, NTOK / 128), blk512, 0, stream>>>(
        avH, avL, woTh, woTl, out, DM, out, nullptr, BIG, DM, 0, nullptr, DM);
}

// Round 9
// 852.807 us; speedup vs baseline: 2.0699x; 1.0195x over previous
//
#include <hip/hip_runtime.h>

// ---------------------------------------------------------------- constants
constexpr int NC  = 16;    // n_chunks
constexpr int LL  = 1024;  // chunk len
constexpr int DM  = 512;   // d_model
constexpr int DI  = 1024;  // d_inner
constexpr int DS  = 16;    // d_state
constexpr int NH  = 8;     // heads
constexpr int DH  = 64;    // head dim
constexpr int NTOK = NC * LL;  // 16384
constexpr int NSEG = 16;   // scan segments
constexpr int TSEG = LL / NSEG;  // 64
constexpr int NF  = 1152;  // fused dbc GEMM padded N (1024 dt + 32 bc + 96 pad)

typedef unsigned short u16;
typedef __attribute__((ext_vector_type(8))) short bf16x8;
typedef __attribute__((ext_vector_type(4))) float f32x4;

__device__ __forceinline__ float softplusf(float x) {
    return x > 20.f ? x : log1pf(__expf(x));
}
__device__ __forceinline__ float siluf(float x) {
    return x / (1.f + __expf(-x));
}
__device__ __forceinline__ float fexp2(float x) {
    return __builtin_amdgcn_exp2f(x);             // v_exp_f32
}
__device__ __forceinline__ float q4(const float4& v, int r) {
    return r == 0 ? v.x : r == 1 ? v.y : r == 2 ? v.z : v.w;  // r compile-time
}
__device__ __forceinline__ u16 f2bf(float f) {    // RNE fp32 -> bf16 bits
    union { float f; unsigned u; } v; v.f = f;
    unsigned u = v.u;
    return (u16)((u + 0x7FFFu + ((u >> 16) & 1u)) >> 16);
}
__device__ __forceinline__ float bf2f(u16 h) {
    union { unsigned u; float f; } v; v.u = (unsigned)h << 16;
    return v.f;
}

// ---------------------------------------------------------------- split (linear)
__global__ __launch_bounds__(256)
void split_kernel(const float* __restrict__ in, u16* __restrict__ hi,
                  u16* __restrict__ lo, int n4)
{
    int i = blockIdx.x * 256 + threadIdx.x;
    if (i >= n4) return;
    float4 v = ((const float4*)in)[i];
    ushort4 h, l;
    h.x = f2bf(v.x); l.x = f2bf(v.x - bf2f(h.x));
    h.y = f2bf(v.y); l.y = f2bf(v.y - bf2f(h.y));
    h.z = f2bf(v.z); l.z = f2bf(v.z - bf2f(h.z));
    h.w = f2bf(v.w); l.w = f2bf(v.w - bf2f(h.w));
    ((ushort4*)hi)[i] = h;
    ((ushort4*)lo)[i] = l;
}

// ---------------------------------------------------------------- splitT
// weights fp32 [K][N] -> bf16 hi/lo [N][K] via LDS 64x64 tile transpose
__global__ __launch_bounds__(256)
void splitT_kernel(const float* __restrict__ in, u16* __restrict__ hi,
                   u16* __restrict__ lo, int K, int N)
{
    __shared__ float tile[64][65];
    const int k0 = blockIdx.y * 64, n0 = blockIdx.x * 64;
    const int tr = threadIdx.x >> 6, tc = threadIdx.x & 63;
#pragma unroll
    for (int i = 0; i < 16; ++i) {
        int r = tr * 16 + i;
        tile[r][tc] = in[(size_t)(k0 + r) * N + n0 + tc];
    }
    __syncthreads();
#pragma unroll
    for (int i = 0; i < 16; ++i) {
        int r = tr * 16 + i;
        float v = tile[tc][r];                    // in[k0+tc][n0+r]
        u16 h = f2bf(v);
        u16 l = f2bf(v - bf2f(h));
        size_t o = (size_t)(n0 + r) * K + k0 + tc;
        hi[o] = h;
        lo[o] = l;
    }
}

// ---------------------------------------------------------------- fused weight
// WfT[n][k] (bf16 hi/lo), n in [0,1056):
//   n < 1024 : (x_proj[:, :32] @ dt_w)[k][n]
//   else     : x_proj[k][32 + n - 1024]         (B|C columns)
__global__ __launch_bounds__(256)
void wfused_kernel(const float* __restrict__ x_proj,   // [1024][64]
                   const float* __restrict__ dt_w,     // [32][1024]
                   u16* __restrict__ wh, u16* __restrict__ wl)
{
    int idx = blockIdx.x * 256 + threadIdx.x;     // n*1024 + k, n in [0,1056)
    int k = idx & 1023;
    int n = idx >> 10;
    float v;
    if (n < 1024) {
        v = 0.f;
#pragma unroll
        for (int r = 0; r < 32; ++r)
            v = fmaf(x_proj[k * 64 + r], dt_w[r * 1024 + n], v);
    } else {
        v = x_proj[k * 64 + 32 + (n - 1024)];
    }
    u16 h = f2bf(v);
    wh[idx] = h;
    wl[idx] = f2bf(v - bf2f(h));
}

// ---------------------------------------------------------------- MFMA GEMM (bf16x3)
// C = Ah*Bh + Ah*Bl + Al*Bh; A split [M][K], B split [N][K].
// MODE 0: plain store. MODE 1: col<nsplit -> C else C2 (same ldc).
// MODE 2: += Cin. MODE 3: col<nsplit -> softplus(+bias) into C;
//         col in [nsplit, nsplit+32) -> C2 (ldc2); else dropped.
// 128x128 tile, BK=32, 512 thr (8 waves 2x4), global_load_lds double-buffered
// 64KB LDS (2 blocks/CU), linear dest + pre-swizzled source, XCD block swizzle.
template<int MODE>
__global__ __launch_bounds__(512, 4)
void mgemm(const u16* __restrict__ Ah, const u16* __restrict__ Al,
           const u16* __restrict__ Bh, const u16* __restrict__ Bl,
           const float* __restrict__ Cin, int ldcin,
           float* __restrict__ C, float* __restrict__ C2, int nsplit, int ldc,
           int ldc2, const float* __restrict__ bias, int K)
{
    __shared__ u16 lds[2][4][128][32];            // 64 KB
    const int tid = threadIdx.x;

    const int gx = gridDim.x;
    const int nwg = gx * gridDim.y;
    int id = blockIdx.y * gx + blockIdx.x;
    id = (id & 7) * (nwg >> 3) + (id >> 3);
    const int bm = (id / gx) * 128, bn = (id % gx) * 128;

    const int lane = tid & 63;
    const int w = tid >> 6, wr = w >> 2, wc = w & 3;
    const int wbase = w * 16;                     // LDS dest row base (uniform/wave)

    // staging: thread -> (row = tid>>2, chunk = tid&3), one 16B load per tile.
    // LDS linear; global chunk pre-swizzled: gchk = chunk ^ ((row>>1)&3)
    const int srow = tid >> 2;
    const int gchk = (tid & 3) ^ ((tid >> 3) & 3);
    const u16* sp[4];
#pragma unroll
    for (int T = 0; T < 4; ++T) {
        const u16* base = T == 0 ? Ah : T == 1 ? Al : T == 2 ? Bh : Bl;
        const int g0 = (T < 2 ? bm : bn);
        sp[T] = base + (size_t)(g0 + srow) * K + gchk * 8;
    }

    f32x4 acc[4][2];
#pragma unroll
    for (int i = 0; i < 4; ++i)
#pragma unroll
        for (int j = 0; j < 2; ++j)
            acc[i][j] = (f32x4){0.f, 0.f, 0.f, 0.f};

    const int nkt = K >> 5;

#define STAGE(b, kt)                                                          \
    {                                                                         \
        _Pragma("unroll")                                                     \
        for (int T = 0; T < 4; ++T)                                           \
            __builtin_amdgcn_global_load_lds(                                 \
                (const __attribute__((address_space(1))) unsigned int*)       \
                    (sp[T] + (size_t)(kt) * 32),                              \
                (__attribute__((address_space(3))) unsigned int*)             \
                    &lds[b][T][wbase][0],                                     \
                16, 0, 0);                                                    \
    }

    STAGE(0, 0);
    int cur = 0;
    for (int kt = 0; kt < nkt; ++kt) {
        asm volatile("s_waitcnt vmcnt(0)" ::: "memory");
        __builtin_amdgcn_s_barrier();
        __builtin_amdgcn_sched_barrier(0);
        if (kt + 1 < nkt) STAGE(cur ^ 1, kt + 1);   // flies under compute
        {
            bf16x8 ah[4], al[4], bh[2], bl[2];
            const int kc = lane >> 4;
#pragma unroll
            for (int mi = 0; mi < 4; ++mi) {
                int row = wr * 64 + mi * 16 + (lane & 15);
                int rc = kc ^ ((row >> 1) & 3);
                ah[mi] = *(const bf16x8*)&lds[cur][0][row][rc * 8];
                al[mi] = *(const bf16x8*)&lds[cur][1][row][rc * 8];
            }
#pragma unroll
            for (int ni = 0; ni < 2; ++ni) {
                int col = wc * 32 + ni * 16 + (lane & 15);
                int rc = kc ^ ((col >> 1) & 3);
                bh[ni] = *(const bf16x8*)&lds[cur][2][col][rc * 8];
                bl[ni] = *(const bf16x8*)&lds[cur][3][col][rc * 8];
            }
#pragma unroll
            for (int mi = 0; mi < 4; ++mi)
#pragma unroll
                for (int ni = 0; ni < 2; ++ni) {
                    acc[mi][ni] = __builtin_amdgcn_mfma_f32_16x16x32_bf16(
                        ah[mi], bh[ni], acc[mi][ni], 0, 0, 0);
                    acc[mi][ni] = __builtin_amdgcn_mfma_f32_16x16x32_bf16(
                        ah[mi], bl[ni], acc[mi][ni], 0, 0, 0);
                    acc[mi][ni] = __builtin_amdgcn_mfma_f32_16x16x32_bf16(
                        al[mi], bh[ni], acc[mi][ni], 0, 0, 0);
                }
        }
        __builtin_amdgcn_sched_barrier(0);
        cur ^= 1;
    }
#undef STAGE

    // epilogue: C/D layout col = lane&15, row = (lane>>4)*4 + r
#pragma unroll
    for (int mi = 0; mi < 4; ++mi) {
        int row0 = bm + wr * 64 + mi * 16 + (lane >> 4) * 4;
#pragma unroll
        for (int ni = 0; ni < 2; ++ni) {
            int col = bn + wc * 32 + ni * 16 + (lane & 15);
            if (MODE == 3) {
                if (col < nsplit) {
#pragma unroll
                    for (int r = 0; r < 4; ++r)
                        C[(size_t)(row0 + r) * ldc + col] =
                            softplusf(acc[mi][ni][r] + bias[col]);
                } else if (col < nsplit + 32) {
#pragma unroll
                    for (int r = 0; r < 4; ++r)
                        C2[(size_t)(row0 + r) * ldc2 + (col - nsplit)] =
                            acc[mi][ni][r];
                }
            } else {
                float* Cp = C; int cc = col;
                if (MODE == 1 && col >= nsplit) { Cp = C2; cc = col - nsplit; }
#pragma unroll
                for (int r = 0; r < 4; ++r) {
                    float v = acc[mi][ni][r];
                    if (MODE == 2) v += Cin[(size_t)(row0 + r) * ldcin + col];
                    Cp[(size_t)(row0 + r) * ldc + cc] = v;
                }
            }
        }
    }
}

// ---------------------------------------------------------------- conv + silu -> bf16 hi/lo
__global__ __launch_bounds__(256)
void conv_kernel(const float* __restrict__ xi, const float* __restrict__ conv_w,
                 const float* __restrict__ conv_b,
                 u16* __restrict__ xcH, u16* __restrict__ xcL)
{
    int idx = blockIdx.x * 256 + threadIdx.x;      // [NTOK*DI)
    int d = idx & (DI - 1);
    int ct = idx >> 10;
    int t = ct & (LL - 1);
    float4 w = *(const float4*)&conv_w[d * 4];
    float acc = conv_b[d];
    if (t >= 3) acc = fmaf(xi[(ct - 3) * DI + d], w.x, acc);
    if (t >= 2) acc = fmaf(xi[(ct - 2) * DI + d], w.y, acc);
    if (t >= 1) acc = fmaf(xi[(ct - 1) * DI + d], w.z, acc);
    acc = fmaf(xi[ct * DI + d], w.w, acc);
    float v = siluf(acc);
    u16 h = f2bf(v);
    xcH[idx] = h;
    xcL[idx] = f2bf(v - bf2f(h));
}

// ---------------------------------------------------------------- scan S1
// bc layout: [NTOK][32], B = cols 0..15, C = cols 16..31
__global__ __launch_bounds__(256)
void scan1_kernel(const float* __restrict__ dtp,
                  const u16* __restrict__ xcH, const u16* __restrict__ xcL,
                  const float* __restrict__ bc, const float* __restrict__ A_log,
                  float* __restrict__ hseg, float* __restrict__ Dsum)
{
    const int tid = threadIdx.x;
    int b = blockIdx.x;
    const int dblk = b & 3;
    const int seg  = (b >> 2) & (NSEG - 1);
    const int c    = b >> 6;
    const int d = dblk * 256 + tid;

    float A2[DS];
#pragma unroll
    for (int s = 0; s < DS; ++s)
        A2[s] = -__expf(A_log[d * DS + s]) * 1.44269504f;
    float h[DS] = {};
    float Dacc = 0.f;

    int idx  = (c * LL + seg * TSEG) * DI + d;
    int bidx = (c * LL + seg * TSEG) * 32;

    for (int t = 0; t < TSEG; ++t) {
        float dt = dtp[idx];
        float xc = bf2f(xcH[idx]) + bf2f(xcL[idx]);
        float4 Bq0 = *(const float4*)&bc[bidx];
        float4 Bq1 = *(const float4*)&bc[bidx + 4];
        float4 Bq2 = *(const float4*)&bc[bidx + 8];
        float4 Bq3 = *(const float4*)&bc[bidx + 12];
        Dacc += dt;
        float dtx = dt * xc;
#pragma unroll
        for (int qi = 0; qi < 4; ++qi) {
            float4 Bv = qi == 0 ? Bq0 : qi == 1 ? Bq1 : qi == 2 ? Bq2 : Bq3;
#pragma unroll
            for (int r = 0; r < 4; ++r) {
                int s = qi * 4 + r;
                float dA = fexp2(dt * A2[s]);
                h[s] = fmaf(dA, h[s], dtx * q4(Bv, r));
            }
        }
        idx += DI; bidx += 32;
    }

    int ho = ((c * NSEG + seg) * DI + d) * DS;
#pragma unroll
    for (int s = 0; s < DS; s += 4)
        *(float4*)&hseg[ho + s] = make_float4(h[s], h[s + 1], h[s + 2], h[s + 3]);
    Dsum[(c * NSEG + seg) * DI + d] = Dacc;
}

// ---------------------------------------------------------------- scan S2
__global__ __launch_bounds__(256)
void scan2_kernel(float* hseg, const float* __restrict__ Dsum,
                  const float* __restrict__ A_log)
{
    int g = blockIdx.x * 256 + threadIdx.x;      // (c*DI+d)*16 + s
    const int s  = g & 15;
    const int cd = g >> 4;
    const int d = cd & (DI - 1);
    const int c = cd >> 10;
    const float A2 = -__expf(A_log[d * DS + s]) * 1.44269504f;

    float h = 0.f;
#pragma unroll
    for (int k = 0; k < NSEG; ++k) {
        int o = ((c * NSEG + k) * DI + d) * DS + s;
        float he = hseg[o];
        float Dk = Dsum[(c * NSEG + k) * DI + d];
        hseg[o] = h;                              // h_in for segment k
        h = fmaf(fexp2(A2 * Dk), h, he);          // carry to k+1
    }
}

// ---------------------------------------------------------------- scan S3
__global__ __launch_bounds__(256)
void scan3_kernel(float* dty,
                  const u16* __restrict__ xcH, const u16* __restrict__ xcL,
                  const float* __restrict__ zp, const float* __restrict__ bc,
                  const float* __restrict__ A_log, const float* __restrict__ Dp,
                  const float* __restrict__ hseg)
{
    const int tid = threadIdx.x;
    int b = blockIdx.x;
    const int dblk = b & 3;
    const int seg  = (b >> 2) & (NSEG - 1);
    const int c    = b >> 6;
    const int d = dblk * 256 + tid;

    float A2[DS];
#pragma unroll
    for (int s = 0; s < DS; ++s)
        A2[s] = -__expf(A_log[d * DS + s]) * 1.44269504f;
    const float Dpd = Dp[d];

    float h[DS];
    int ho = ((c * NSEG + seg) * DI + d) * DS;
#pragma unroll
    for (int s = 0; s < DS; s += 4) {
        float4 hv = *(const float4*)&hseg[ho + s];
        h[s] = hv.x; h[s + 1] = hv.y; h[s + 2] = hv.z; h[s + 3] = hv.w;
    }

    int idx  = (c * LL + seg * TSEG) * DI + d;
    int bidx = (c * LL + seg * TSEG) * 32;

    float ndt = dty[idx];
    float nxc = bf2f(xcH[idx]) + bf2f(xcL[idx]);
    float nz = zp[idx];

    for (int t = 0; t < TSEG; ++t) {
        float dt = ndt, xc = nxc, z = nz;
        if (t + 1 < TSEG) {
            ndt = dty[idx + DI];
            nxc = bf2f(xcH[idx + DI]) + bf2f(xcL[idx + DI]);
            nz = zp[idx + DI];
        }
        float4 Bq0 = *(const float4*)&bc[bidx];
        float4 Bq1 = *(const float4*)&bc[bidx + 4];
        float4 Bq2 = *(const float4*)&bc[bidx + 8];
        float4 Bq3 = *(const float4*)&bc[bidx + 12];
        float4 Cq0 = *(const float4*)&bc[bidx + 16];
        float4 Cq1 = *(const float4*)&bc[bidx + 20];
        float4 Cq2 = *(const float4*)&bc[bidx + 24];
        float4 Cq3 = *(const float4*)&bc[bidx + 28];
        float dtx = dt * xc;
        float yt = 0.f;
#pragma unroll
        for (int qi = 0; qi < 4; ++qi) {
            float4 Bv = qi == 0 ? Bq0 : qi == 1 ? Bq1 : qi == 2 ? Bq2 : Bq3;
            float4 Cv = qi == 0 ? Cq0 : qi == 1 ? Cq1 : qi == 2 ? Cq2 : Cq3;
#pragma unroll
            for (int r = 0; r < 4; ++r) {
                int s = qi * 4 + r;
                float dA = fexp2(dt * A2[s]);
                h[s] = fmaf(dA, h[s], dtx * q4(Bv, r));
                yt = fmaf(h[s], q4(Cv, r), yt);
            }
        }
        dty[idx] = (yt + xc * Dpd) * siluf(z);
        idx += DI; bidx += 32;
    }
}

// ---------------------------------------------------------------- mean over L
__global__ __launch_bounds__(64)
void mean_kernel(const float* __restrict__ chunks, float* __restrict__ meanb)
{
    int j = blockIdx.x * 64 + threadIdx.x;
    int c = blockIdx.y;
    float s = 0.f;
    for (int t = 0; t < LL; ++t) s += chunks[(c * LL + t) * DM + j];
    meanb[c * DM + j] = s * (1.f / LL);
}

// ---------------------------------------------------------------- summaries
__global__ __launch_bounds__(256)
void summ_kernel(const float* __restrict__ meanb, const float* __restrict__ sum_w,
                 const float* __restrict__ sum_b, float* __restrict__ summ)
{
    int n = blockIdx.x * 256 + threadIdx.x;
    int c = blockIdx.y;
    float acc = sum_b[n];
    for (int k = 0; k < DM; ++k) acc = fmaf(meanb[c * DM + k], sum_w[k * DM + n], acc);
    summ[c * DM + n] = acc;
}

__global__ __launch_bounds__(256)
void kv_kernel(const float* __restrict__ summ, const float* __restrict__ wk,
               const float* __restrict__ wv, float* __restrict__ kb,
               float* __restrict__ vb)
{
    int n = blockIdx.x * 256 + threadIdx.x;
    int c = blockIdx.y;
    float ak = 0.f, av = 0.f;
    for (int k = 0; k < DM; ++k) {
        float s = summ[c * DM + k];
        ak = fmaf(s, wk[k * DM + n], ak);
        av = fmaf(s, wv[k * DM + n], av);
    }
    kb[c * DM + n] = ak;
    vb[c * DM + n] = av;
}

// ---------------------------------------------------------------- cross-attn
__global__ __launch_bounds__(128)
void attn_kernel(float* qv,                      // [NTOK, DM] q in / attnv out
                 const float* __restrict__ kb,   // [NC, DM]
                 const float* __restrict__ vb)   // [NC, DM]
{
    __shared__ float sq[DM];
    __shared__ float sAttn[NH][NC];
    const int ct = blockIdx.x;
    const int c = ct >> 10;
    const int tid = threadIdx.x;

    *(float4*)&sq[tid * 4] = *(const float4*)&qv[ct * DM + tid * 4];
    __syncthreads();

    const int h = tid >> 4, j = tid & 15;
    const float* kr = kb + j * DM + h * DH;
    const float* qr = sq + h * DH;
    float s = 0.f;
#pragma unroll
    for (int d0 = 0; d0 < DH; d0 += 4) {
        float4 k4 = *(const float4*)&kr[d0];
        float4 qv4 = *(const float4*)&qr[d0];
        s += qv4.x * k4.x + qv4.y * k4.y + qv4.z * k4.z + qv4.w * k4.w;
    }
    s *= 0.125f;                                  // 1/sqrt(64)
    if (j == c) s = -__builtin_inff();

    float m = s;
#pragma unroll
    for (int o = 1; o < 16; o <<= 1) m = fmaxf(m, __shfl_xor(m, o));
    float e = __expf(s - m);
    float sum = e;
#pragma unroll
    for (int o = 1; o < 16; o <<= 1) sum += __shfl_xor(sum, o);
    sAttn[h][j] = e / sum;
    __syncthreads();

#pragma unroll
    for (int r = 0; r < 4; ++r) {
        int o = r * 128 + tid;
        int h2 = o >> 6;
        float acc = 0.f;
#pragma unroll
        for (int jj = 0; jj < NC; ++jj)
            acc = fmaf(sAttn[h2][jj], vb[jj * DM + o], acc);
        qv[ct * DM + o] = acc;
    }
}

// ---------------------------------------------------------------- launch
extern "C" void kernel_launch(void* const* d_in, const int* in_sizes, int n_in,
                              void* d_out, int out_size, void* d_ws, size_t ws_size,
                              hipStream_t stream)
{
    const float* chunks   = (const float*)d_in[0];
    const float* in_proj  = (const float*)d_in[1];
    const float* conv_w   = (const float*)d_in[2];
    const float* conv_b   = (const float*)d_in[3];
    const float* x_proj   = (const float*)d_in[4];
    const float* dt_w     = (const float*)d_in[5];
    const float* dt_b     = (const float*)d_in[6];
    const float* A_log    = (const float*)d_in[7];
    const float* Dp       = (const float*)d_in[8];
    const float* out_proj = (const float*)d_in[9];
    const float* sum_w    = (const float*)d_in[10];
    const float* sum_b    = (const float*)d_in[11];
    const float* wq       = (const float*)d_in[12];
    const float* wk       = (const float*)d_in[13];
    const float* wv       = (const float*)d_in[14];
    const float* wo       = (const float*)d_in[15];
    float* out = (float*)d_out;

    // -------- workspace layout: same ~214 MB footprint as R8
    float* ws   = (float*)d_ws;
    float* bufA = ws;                            // [NTOK,DI] xi -> dt -> y -> {tokH/L, avH/L}
    float* bufB = bufA + (size_t)NTOK * DI;      // [NTOK,DI] z -> q -> attnv
    float* bufC = bufB + (size_t)NTOK * DI;      // [NTOK,DI] {chH/L} -> {xcH/L} -> {yH/L}
    float* dbc  = bufC + (size_t)NTOK * DI;      // [NTOK,32] bc (B|C)
    float* meanb= dbc + (size_t)NTOK * 64;       // [16,512]
    float* summ = meanb + NC * DM;
    float* kb   = summ + NC * DM;
    float* vb   = kb + NC * DM;
    float* hseg = vb + NC * DM;                  // [NC,NSEG,DI,DS] 16.8MB; aliases ipT+WfT then {opT,wqT,woT}
    float* Dsum = hseg + (size_t)NC * NSEG * DI * DS;  // [NC,NSEG,DI]

    // u16 aliases (lifetimes verified)
    u16* chH  = (u16*)bufC;                      // [NTOK,DM] dead after G1
    u16* chL  = chH + (size_t)NTOK * DM;
    u16* xcH  = (u16*)bufC;                      // [NTOK,DI] conv output (overwrites chH/L)
    u16* xcL  = xcH + (size_t)NTOK * DI;
    u16* yH   = (u16*)bufC;                      // [NTOK,DI] written after scan3 (xc dead)
    u16* yL   = yH + (size_t)NTOK * DI;
    u16* tokH = (u16*)bufA;                      // [NTOK,DM] written after G4 (y dead)
    u16* tokL = tokH + (size_t)NTOK * DM;
    u16* avH  = (u16*)bufA + (size_t)NTOK * DI;  // bufA second half
    u16* avL  = avH + (size_t)NTOK * DM;
    u16* ipTh = (u16*)hseg;                      // [2048,512] dead after G1
    u16* ipTl = ipTh + (size_t)2048 * 512;
    u16* WfTh = ipTl + (size_t)2048 * 512;       // [NF,1024] fused weight (rows 0..1055 valid)
    u16* WfTl = WfTh + (size_t)NF * 1024;        // ends at ~8.9MB < 16.8MB region
    u16* opTh = (u16*)hseg;                      // written after scan3 (hseg dead)
    u16* opTl = opTh + (size_t)512 * 1024;
    u16* wqTh = opTl + (size_t)512 * 1024;
    u16* wqTl = wqTh + (size_t)512 * 512;
    u16* woTh = wqTl + (size_t)512 * 512;
    u16* woTl = woTh + (size_t)512 * 512;

    dim3 blk512(512), blk256(256), blk128(128), blk64(64);
    const int BIG = 1 << 30;

    // ---- weight prep + input split
    splitT_kernel<<<dim3(2048 / 64, 512 / 64), blk256, 0, stream>>>(in_proj, ipTh, ipTl, 512, 2048);
    wfused_kernel<<<1056 * 1024 / 256, blk256, 0, stream>>>(x_proj, dt_w, WfTh, WfTl);
    split_kernel<<<NTOK * DM / 4 / 256, blk256, 0, stream>>>(chunks, chH, chL, NTOK * DM / 4);
    // G1: [xi | z] = chunks @ in_proj  (M=16384, N=2048, K=512)
    mgemm<1><<<dim3(2048 / 128, NTOK / 128), blk512, 0, stream>>>(
        chH, chL, ipTh, ipTl, nullptr, 0, bufA, bufB, 1024, DI, DI, nullptr, DM);
    // conv + silu -> xcH/xcL (bufC; chH/L dead)
    conv_kernel<<<NTOK * DI / 256, blk256, 0, stream>>>(bufA, conv_w, conv_b, xcH, xcL);
    // fused dbc GEMM: dt = softplus(xc@Wdt + dt_b) -> bufA; B|C -> dbc
    mgemm<3><<<dim3(NF / 128, NTOK / 128), blk512, 0, stream>>>(
        xcH, xcL, WfTh, WfTl, nullptr, 0, bufA, dbc, 1024, DI, 32, dt_b, DI);
    // scan: 3-phase segmented (scan1 overwrites ipT/WfT with hseg — both dead)
    scan1_kernel<<<NC * NSEG * (DI / 256), blk256, 0, stream>>>(bufA, xcH, xcL, dbc, A_log, hseg, Dsum);
    scan2_kernel<<<NC * DI * DS / 256, blk256, 0, stream>>>(hseg, Dsum, A_log);
    scan3_kernel<<<NC * NSEG * (DI / 256), blk256, 0, stream>>>(bufA, xcH, xcL, bufB, dbc, A_log, Dp, hseg);
    // split y (bufA) -> yH/yL in bufC (xc dead)
    split_kernel<<<NTOK * DI / 4 / 256, blk256, 0, stream>>>(bufA, yH, yL, NTOK * DI / 4);
    // split remaining weights into hseg region (hseg dead after scan3)
    splitT_kernel<<<dim3(512 / 64, 1024 / 64), blk256, 0, stream>>>(out_proj, opTh, opTl, 1024, 512);
    splitT_kernel<<<dim3(512 / 64, 512 / 64), blk256, 0, stream>>>(wq, wqTh, wqTl, 512, 512);
    splitT_kernel<<<dim3(512 / 64, 512 / 64), blk256, 0, stream>>>(wo, woTh, woTl, 512, 512);
    // G4: tok = y @ out_proj -> d_out used as scratch (fully overwritten)
    mgemm<0><<<dim3(DM / 128, NTOK / 128), blk512, 0, stream>>>(
        yH, yL, opTh, opTl, nullptr, 0, out, nullptr, BIG, DM, 0, nullptr, DI);
    // summaries
    mean_kernel<<<dim3(DM / 64, NC), blk64, 0, stream>>>(chunks, meanb);
    summ_kernel<<<dim3(2, NC), blk256, 0, stream>>>(meanb, sum_w, sum_b, summ);
    kv_kernel<<<dim3(2, NC), blk256, 0, stream>>>(summ, wk, wv, kb, vb);
    // split tok (d_out) -> tokH/tokL in bufA (y dead)
    split_kernel<<<NTOK * DM / 4 / 256, blk256, 0, stream>>>(out, tokH, tokL, NTOK * DM / 4);
    // G5: q = tok @ wq -> bufB (z dead)
    mgemm<0><<<dim3(DM / 128, NTOK / 128), blk512, 0, stream>>>(
        tokH, tokL, wqTh, wqTl, nullptr, 0, bufB, nullptr, BIG, DM, 0, nullptr, DM);
    // attn: in-place on bufB rows
    attn_kernel<<<NTOK, blk128, 0, stream>>>(bufB, kb, vb);
    // split attnv (bufB) -> avH/avL (bufA second half; tok split dead after G5)
    split_kernel<<<NTOK * DM / 4 / 256, blk256, 0, stream>>>(bufB, avH, avL, NTOK * DM / 4);
    // G6: out = tok + attnv @ wo  (Cin = d_out read-then-write, same thread)
    mgemm<2><<<dim3(DM / 128, NTOK / 128), blk512, 0, stream>>>(
        avH, avL, woTh, woTl, out, DM, out, nullptr, BIG, DM, 0, nullptr, DM);
}